// Round 3
// baseline (1001.487 us; speedup 1.0000x reference)
//
#include <hip/hip_runtime.h>
#include <math.h>

#define N_NODES 100000
#define E_EDGES 1600000
#define D_IN 64
#define HID1 128
#define HID2 64
#define ATT 32
#define CHUNK 1024
#define NB_SCAN ((N_NODES + CHUNK - 1) / CHUNK)   // 98

typedef unsigned int uint32;

__device__ inline unsigned f2o(float f){ unsigned u = __float_as_uint(f); return (u >> 31) ? ~u : (u | 0x80000000u); }
__device__ inline float o2f(unsigned u){ return (u >> 31) ? __uint_as_float(u & 0x7fffffffu) : __uint_as_float(~u); }

// bf16 pack (RNE) / unpack (exact)
__device__ inline uint32 bf16rn(float f){ uint32 u = __float_as_uint(f); return (u + 0x7fffu + ((u >> 16) & 1u)) >> 16; }
__device__ inline uint32 packbf2(float a, float b){ return bf16rn(a) | (bf16rn(b) << 16); }
__device__ inline float2 unpackbf2(uint32 v){ float2 r; r.x = __uint_as_float(v << 16); r.y = __uint_as_float(v & 0xffff0000u); return r; }

__global__ void k_init(float* pooled, float* Z, unsigned* maxu){
    int t = threadIdx.x;
    if (t < 64) pooled[t] = 0.f;
    if (t == 64) *Z = 0.f;
    if (t == 65) *maxu = f2o(-INFINITY);
}

// x (N x 64 fp32) -> packed bf162 table (N x 32 uint)
__global__ void k_xcast(const float* __restrict__ x, uint32* __restrict__ xb){
    int i = blockIdx.x * 256 + threadIdx.x;
    if (i < N_NODES * 32){
        float2 v = ((const float2*)x)[i];
        xb[i] = packbf2(v.x, v.y);
    }
}

__global__ void k_hist(const int* __restrict__ dst, int* __restrict__ cnt){
    int i = blockIdx.x * blockDim.x + threadIdx.x;
    if (i < E_EDGES) atomicAdd(&cnt[dst[i]], 1);
}

__global__ void k_scan1(const int* __restrict__ cnt, int* __restrict__ bsum){
    int base = blockIdx.x * CHUNK + threadIdx.x * 4;
    int s = 0;
    #pragma unroll
    for (int k = 0; k < 4; k++){ int i = base + k; if (i < N_NODES) s += cnt[i]; }
    #pragma unroll
    for (int off = 32; off >= 1; off >>= 1) s += __shfl_down(s, off, 64);
    __shared__ int sm[4];
    if ((threadIdx.x & 63) == 0) sm[threadIdx.x >> 6] = s;
    __syncthreads();
    if (threadIdx.x == 0) bsum[blockIdx.x] = sm[0] + sm[1] + sm[2] + sm[3];
}

__global__ void k_scan2(const int* __restrict__ bsum, int* __restrict__ bscan){
    __shared__ int sb[NB_SCAN];
    int t = threadIdx.x;
    if (t < NB_SCAN) sb[t] = bsum[t];
    __syncthreads();
    if (t == 0){ int run = 0; for (int i = 0; i < NB_SCAN; i++){ int v = sb[i]; sb[i] = run; run += v; } }
    __syncthreads();
    if (t < NB_SCAN) bscan[t] = sb[t];
}

__global__ void k_scan3(const int* __restrict__ cnt, const int* __restrict__ bscan,
                        int* __restrict__ rowptr, int* __restrict__ rowcur){
    __shared__ int ts[256];
    int t = threadIdx.x;
    int base = blockIdx.x * CHUNK + t * 4;
    int v[4]; int s = 0;
    #pragma unroll
    for (int k = 0; k < 4; k++){ int i = base + k; v[k] = (i < N_NODES) ? cnt[i] : 0; s += v[k]; }
    ts[t] = s;
    __syncthreads();
    int total = s;
    for (int off = 1; off < 256; off <<= 1){
        int a = 0;
        if (t >= off) a = ts[t - off];
        __syncthreads();
        ts[t] += a;
        __syncthreads();
    }
    int excl = ts[t] - total + bscan[blockIdx.x];
    #pragma unroll
    for (int k = 0; k < 4; k++){
        int i = base + k;
        if (i < N_NODES){ rowptr[i] = excl; rowcur[i] = excl; excl += v[k]; }
    }
}

__global__ void k_scatter(const int* __restrict__ src, const int* __restrict__ dst,
                          int* __restrict__ rowcur, int* __restrict__ ssrc){
    int i = blockIdx.x * blockDim.x + threadIdx.x;
    if (i < E_EDGES){
        int d = dst[i];
        int pos = atomicAdd(&rowcur[d], 1);
        ssrc[pos] = src[i];
    }
}

// pull-mean(xb) + layer1 -> h1b (packed bf162). One wave per node, 4 nodes/block.
// xb row = 32 uints; half-wave per edge => 2 edges per load instruction.
__global__ void k_fused1(const float* __restrict__ x, const uint32* __restrict__ xb,
                         const int* __restrict__ ssrc, const int* __restrict__ rowptr,
                         const int* __restrict__ cnt,
                         const float* __restrict__ W1l, const float* __restrict__ W1r,
                         const float* __restrict__ b1, uint32* __restrict__ h1b){
    __shared__ float smean[4][64], sx[4][64];
    int g = threadIdx.x >> 6, lane = threadIdx.x & 63;
    int n = blockIdx.x * 4 + g;
    int beg = rowptr[n], c = cnt[n], end = beg + c;
    int p = lane & 31, which = lane >> 5;
    float ax = 0.f, ay = 0.f;
    int e = beg;
    for (; e + 8 <= end; e += 8){
        int s0 = ssrc[e + which], s1 = ssrc[e + 2 + which], s2 = ssrc[e + 4 + which], s3 = ssrc[e + 6 + which];
        float2 v0 = unpackbf2(xb[(size_t)s0 * 32 + p]);
        float2 v1 = unpackbf2(xb[(size_t)s1 * 32 + p]);
        float2 v2 = unpackbf2(xb[(size_t)s2 * 32 + p]);
        float2 v3 = unpackbf2(xb[(size_t)s3 * 32 + p]);
        ax += v0.x + v1.x + v2.x + v3.x;
        ay += v0.y + v1.y + v2.y + v3.y;
    }
    for (; e + 2 <= end; e += 2){
        int s = ssrc[e + which];
        float2 v = unpackbf2(xb[(size_t)s * 32 + p]);
        ax += v.x; ay += v.y;
    }
    if (e < end && which == 0){
        int s = ssrc[e];
        float2 v = unpackbf2(xb[(size_t)s * 32 + p]);
        ax += v.x; ay += v.y;
    }
    ax += __shfl_xor(ax, 32, 64);
    ay += __shfl_xor(ay, 32, 64);
    float inv = 1.f / fmaxf((float)c, 1.f);
    if (which == 0){ smean[g][2 * p] = ax * inv; smean[g][2 * p + 1] = ay * inv; }
    sx[g][lane] = x[(size_t)n * 64 + lane];
    __syncthreads();
    // lane computes output cols 2*lane, 2*lane+1
    const float2* W1l2 = (const float2*)W1l;
    const float2* W1r2 = (const float2*)W1r;
    float a0 = b1[2 * lane], a1 = b1[2 * lane + 1];
    #pragma unroll 8
    for (int k = 0; k < 64; k++){
        float m = smean[g][k], xv = sx[g][k];
        float2 wl = W1l2[k * 64 + lane];
        float2 wr = W1r2[k * 64 + lane];
        a0 += m * wl.x + xv * wr.x;
        a1 += m * wl.y + xv * wr.y;
    }
    h1b[(size_t)n * 64 + lane] = packbf2(fmaxf(a0, 0.f), fmaxf(a1, 0.f));
}

// pull-mean(h1b) + layer2 + attention logit. One wave per node, 4 nodes/block.
// h1b row = 64 uints; 1 edge per load instruction (4B/lane).
__global__ void k_fused2(const float* __restrict__ x, const uint32* __restrict__ h1b,
                         const int* __restrict__ ssrc, const int* __restrict__ rowptr,
                         const int* __restrict__ cnt,
                         const float* __restrict__ W2l, const float* __restrict__ W2r,
                         const float* __restrict__ b2,
                         const float* __restrict__ Wa, const float* __restrict__ ba,
                         const float* __restrict__ ctx,
                         float* __restrict__ h2, float* __restrict__ wlogit){
    __shared__ float smean[4][128], sh[4][128], sh2[4][64];
    int g = threadIdx.x >> 6, lane = threadIdx.x & 63;
    int n = blockIdx.x * 4 + g;
    int beg = rowptr[n], c = cnt[n], end = beg + c;
    float ax = 0.f, ay = 0.f;
    int e = beg;
    for (; e + 4 <= end; e += 4){
        int s0 = ssrc[e], s1 = ssrc[e + 1], s2 = ssrc[e + 2], s3 = ssrc[e + 3];
        float2 v0 = unpackbf2(h1b[(size_t)s0 * 64 + lane]);
        float2 v1 = unpackbf2(h1b[(size_t)s1 * 64 + lane]);
        float2 v2 = unpackbf2(h1b[(size_t)s2 * 64 + lane]);
        float2 v3 = unpackbf2(h1b[(size_t)s3 * 64 + lane]);
        ax += v0.x + v1.x + v2.x + v3.x;
        ay += v0.y + v1.y + v2.y + v3.y;
    }
    for (; e < end; e++){
        float2 v = unpackbf2(h1b[(size_t)ssrc[e] * 64 + lane]);
        ax += v.x; ay += v.y;
    }
    float inv = 1.f / fmaxf((float)c, 1.f);
    smean[g][2 * lane] = ax * inv;
    smean[g][2 * lane + 1] = ay * inv;
    float2 sv = unpackbf2(h1b[(size_t)n * 64 + lane]);
    sh[g][2 * lane] = sv.x;
    sh[g][2 * lane + 1] = sv.y;
    __syncthreads();
    float suml = 0.f, sumr = b2[lane];
    #pragma unroll 8
    for (int k = 0; k < 128; k++){
        suml += smean[g][k] * W2l[k * 64 + lane];
        sumr += sh[g][k]    * W2r[k * 64 + lane];
    }
    float v = fmaxf(suml + sumr, 0.f);
    sh2[g][lane] = v;
    h2[(size_t)n * 64 + lane] = v;
    __syncthreads();
    float pa = 0.f;
    if (lane < ATT){
        float s = ba[lane];
        #pragma unroll 8
        for (int j = 0; j < 64; j++) s += sh2[g][j] * Wa[j * ATT + lane];
        pa = tanhf(s) * ctx[lane];
    }
    #pragma unroll
    for (int off = 16; off >= 1; off >>= 1) pa += __shfl_down(pa, off, 64);
    if (lane == 0) wlogit[n] = pa + x[(size_t)n * 64 + 63] * 0.4f;
}

__global__ void k_max(const float* __restrict__ wlogit, unsigned* __restrict__ maxu){
    float m = -INFINITY;
    for (size_t i = (size_t)blockIdx.x * blockDim.x + threadIdx.x; i < N_NODES; i += (size_t)gridDim.x * blockDim.x)
        m = fmaxf(m, wlogit[i]);
    #pragma unroll
    for (int off = 32; off >= 1; off >>= 1) m = fmaxf(m, __shfl_down(m, off, 64));
    __shared__ float sm[4];
    if ((threadIdx.x & 63) == 0) sm[threadIdx.x >> 6] = m;
    __syncthreads();
    if (threadIdx.x == 0){
        float mm = fmaxf(fmaxf(sm[0], sm[1]), fmaxf(sm[2], sm[3]));
        atomicMax(maxu, f2o(mm));
    }
}

__global__ void k_pool(const float* __restrict__ h2, const float* __restrict__ wlogit,
                       const unsigned* __restrict__ maxu, float* __restrict__ pooled, float* __restrict__ Z){
    float mv = o2f(*maxu);
    int lane = threadIdx.x & 63;
    int row  = threadIdx.x >> 6;
    float pacc = 0.f, zacc = 0.f;
    for (size_t n = (size_t)blockIdx.x * 4 + row; n < N_NODES; n += (size_t)gridDim.x * 4){
        float e = expf(wlogit[n] - mv);
        pacc += h2[n * 64 + lane] * e;
        zacc += e;
    }
    __shared__ float sp[4][64];
    sp[row][lane] = pacc;
    __syncthreads();
    if (threadIdx.x < 64){
        float s = sp[0][threadIdx.x] + sp[1][threadIdx.x] + sp[2][threadIdx.x] + sp[3][threadIdx.x];
        atomicAdd(&pooled[threadIdx.x], s);
    }
    if (lane == 0) atomicAdd(Z, zacc);
}

__global__ void k_final(const float* __restrict__ pooled, const float* __restrict__ Z,
                        const float* __restrict__ Wc1, const float* __restrict__ bc1,
                        const float* __restrict__ Wc2, const float* __restrict__ bc2,
                        float* __restrict__ out){
    __shared__ float sp[64], sz[32];
    int t = threadIdx.x;
    float scale = 1.0f / ((*Z) * (float)N_NODES);
    sp[t] = pooled[t] * scale;
    __syncthreads();
    if (t < 32){
        float s = bc1[t];
        #pragma unroll 8
        for (int j = 0; j < 64; j++) s += sp[j] * Wc1[j * 32 + t];
        sz[t] = fmaxf(s, 0.f);
    }
    __syncthreads();
    if (t == 0){
        float s = bc2[0];
        #pragma unroll
        for (int i = 0; i < 32; i++) s += sz[i] * Wc2[i];
        out[0] = 1.0f / (1.0f + expf(-s));
    }
}

extern "C" void kernel_launch(void* const* d_in, const int* in_sizes, int n_in,
                              void* d_out, int out_size, void* d_ws, size_t ws_size,
                              hipStream_t stream) {
    const float* x   = (const float*)d_in[0];
    const int*   ei  = (const int*)d_in[1];
    const int*   src = ei;
    const int*   dst = ei + E_EDGES;
    const float* W1l = (const float*)d_in[2];
    const float* W1r = (const float*)d_in[3];
    const float* b1  = (const float*)d_in[4];
    const float* W2l = (const float*)d_in[5];
    const float* W2r = (const float*)d_in[6];
    const float* b2  = (const float*)d_in[7];
    const float* Wa  = (const float*)d_in[8];
    const float* ba  = (const float*)d_in[9];
    const float* ctx = (const float*)d_in[10];
    const float* Wc1 = (const float*)d_in[11];
    const float* bc1 = (const float*)d_in[12];
    const float* Wc2 = (const float*)d_in[13];
    const float* bc2 = (const float*)d_in[14];

    char* p = (char*)d_ws;
    int* cnt    = (int*)p;                 p += (size_t)N_NODES * 4;
    int* rowptr = (int*)p;                 p += (size_t)N_NODES * 4;
    int* rowcur = (int*)p;                 p += (size_t)N_NODES * 4;
    int* bsum   = (int*)p;                 p += 128 * 4;
    int* bscan  = (int*)p;                 p += 128 * 4;
    int* ssrc   = (int*)p;                 p += (size_t)E_EDGES * 4;
    uint32* xb  = (uint32*)p;              p += (size_t)N_NODES * 32 * 4;
    uint32* h1b = (uint32*)p;              p += (size_t)N_NODES * 64 * 4;
    float* h2     = (float*)p;             p += (size_t)N_NODES * 64 * 4;
    float* wlogit = (float*)p;             p += (size_t)N_NODES * 4;
    float* pooled = (float*)p;             p += 64 * 4;
    float* Zp     = (float*)p;             p += 4;
    unsigned* maxu = (unsigned*)p;

    hipMemsetAsync(cnt, 0, (size_t)N_NODES * 4, stream);
    k_init<<<1, 128, 0, stream>>>(pooled, Zp, maxu);

    k_xcast<<<(N_NODES * 32 + 255) / 256, 256, 0, stream>>>(x, xb);
    k_hist<<<(E_EDGES + 255) / 256, 256, 0, stream>>>(dst, cnt);
    k_scan1<<<NB_SCAN, 256, 0, stream>>>(cnt, bsum);
    k_scan2<<<1, 128, 0, stream>>>(bsum, bscan);
    k_scan3<<<NB_SCAN, 256, 0, stream>>>(cnt, bscan, rowptr, rowcur);
    k_scatter<<<(E_EDGES + 255) / 256, 256, 0, stream>>>(src, dst, rowcur, ssrc);

    k_fused1<<<N_NODES / 4, 256, 0, stream>>>(x, xb, ssrc, rowptr, cnt, W1l, W1r, b1, h1b);
    k_fused2<<<N_NODES / 4, 256, 0, stream>>>(x, h1b, ssrc, rowptr, cnt, W2l, W2r, b2, Wa, ba, ctx, h2, wlogit);

    k_max<<<512, 256, 0, stream>>>(wlogit, maxu);
    k_pool<<<1024, 256, 0, stream>>>(h2, wlogit, maxu, pooled, Zp);
    k_final<<<1, 64, 0, stream>>>(pooled, Zp, Wc1, bc1, Wc2, bc2, (float*)d_out);
}

// Round 4
// 572.273 us; speedup vs baseline: 1.7500x; 1.7500x over previous
//
#include <hip/hip_runtime.h>
#include <math.h>

#define N_NODES 100000
#define E_EDGES 1600000
#define D_IN 64
#define HID1 128
#define HID2 64
#define ATT 32
#define CHUNK 1024
#define NB_SCAN ((N_NODES + CHUNK - 1) / CHUNK)   // 98
#define AT_STRIDE 136   // 128 + 8 bf16 pad: keeps ds_read_b128 16B-aligned, 2-way banks

typedef unsigned int uint32;
typedef unsigned short ushort;
typedef __attribute__((ext_vector_type(8))) short short8;
typedef __attribute__((ext_vector_type(4))) float float4v;

__device__ inline unsigned f2o(float f){ unsigned u = __float_as_uint(f); return (u >> 31) ? ~u : (u | 0x80000000u); }
__device__ inline float o2f(unsigned u){ return (u >> 31) ? __uint_as_float(u & 0x7fffffffu) : __uint_as_float(~u); }

__device__ inline uint32 bf16rn(float f){ uint32 u = __float_as_uint(f); return (u + 0x7fffu + ((u >> 16) & 1u)) >> 16; }
__device__ inline uint32 packbf2(float a, float b){ return bf16rn(a) | (bf16rn(b) << 16); }
__device__ inline float2 unpackbf2(uint32 v){ float2 r; r.x = __uint_as_float(v << 16); r.y = __uint_as_float(v & 0xffff0000u); return r; }

__global__ void k_init(float* pooled, float* Z, unsigned* maxu){
    int t = threadIdx.x;
    if (t < 64) pooled[t] = 0.f;
    if (t == 64) *Z = 0.f;
    if (t == 65) *maxu = f2o(-INFINITY);
}

// x (N x 64 fp32) -> packed bf162 table (N x 32 uint)
__global__ void k_xcast(const float* __restrict__ x, uint32* __restrict__ xb){
    int i = blockIdx.x * 256 + threadIdx.x;
    if (i < N_NODES * 32){
        float2 v = ((const float2*)x)[i];
        xb[i] = packbf2(v.x, v.y);
    }
}

// one-time: build transposed bf16 weight tables wt[n][k] (128x128 each)
// block 0: [W1l;W1r] (k<64 -> W1l[k][n], else W1r[k-64][n])
// block 1: [W2l|W2r] (n<64 -> W2l[k][n], else W2r[k][n-64])
__global__ void k_prep(const float* __restrict__ W1l, const float* __restrict__ W1r,
                       const float* __restrict__ W2l, const float* __restrict__ W2r,
                       ushort* __restrict__ wt1g, ushort* __restrict__ wt2g){
    __shared__ ushort st[128 * 130];
    int t = threadIdx.x;
    int n = t & 127, kh = t >> 7;
    if (blockIdx.x == 0){
        for (int k0 = 0; k0 < 128; k0 += 2){
            int k = k0 + kh;
            float v = (k < 64) ? W1l[k * 128 + n] : W1r[(k - 64) * 128 + n];
            st[k * 130 + n] = (ushort)bf16rn(v);
        }
    } else {
        for (int k0 = 0; k0 < 128; k0 += 2){
            int k = k0 + kh;
            float v = (n < 64) ? W2l[k * 64 + n] : W2r[k * 64 + (n - 64)];
            st[k * 130 + n] = (ushort)bf16rn(v);
        }
    }
    __syncthreads();
    ushort* dstp = (blockIdx.x == 0) ? wt1g : wt2g;
    int kk = t & 127, nh = t >> 7;
    for (int n0 = 0; n0 < 128; n0 += 2){
        int nn = n0 + nh;
        dstp[nn * 128 + kk] = st[kk * 130 + nn];
    }
}

__global__ void k_hist(const int* __restrict__ dst, int* __restrict__ cnt){
    int i = blockIdx.x * blockDim.x + threadIdx.x;
    if (i < E_EDGES) atomicAdd(&cnt[dst[i]], 1);
}

__global__ void k_scan1(const int* __restrict__ cnt, int* __restrict__ bsum){
    int base = blockIdx.x * CHUNK + threadIdx.x * 4;
    int s = 0;
    #pragma unroll
    for (int k = 0; k < 4; k++){ int i = base + k; if (i < N_NODES) s += cnt[i]; }
    #pragma unroll
    for (int off = 32; off >= 1; off >>= 1) s += __shfl_down(s, off, 64);
    __shared__ int sm[4];
    if ((threadIdx.x & 63) == 0) sm[threadIdx.x >> 6] = s;
    __syncthreads();
    if (threadIdx.x == 0) bsum[blockIdx.x] = sm[0] + sm[1] + sm[2] + sm[3];
}

__global__ void k_scan2(const int* __restrict__ bsum, int* __restrict__ bscan){
    __shared__ int sb[NB_SCAN];
    int t = threadIdx.x;
    if (t < NB_SCAN) sb[t] = bsum[t];
    __syncthreads();
    if (t == 0){ int run = 0; for (int i = 0; i < NB_SCAN; i++){ int v = sb[i]; sb[i] = run; run += v; } }
    __syncthreads();
    if (t < NB_SCAN) bscan[t] = sb[t];
}

__global__ void k_scan3(const int* __restrict__ cnt, const int* __restrict__ bscan,
                        int* __restrict__ rowptr, int* __restrict__ rowcur){
    __shared__ int ts[256];
    int t = threadIdx.x;
    int base = blockIdx.x * CHUNK + t * 4;
    int v[4]; int s = 0;
    #pragma unroll
    for (int k = 0; k < 4; k++){ int i = base + k; v[k] = (i < N_NODES) ? cnt[i] : 0; s += v[k]; }
    ts[t] = s;
    __syncthreads();
    int total = s;
    for (int off = 1; off < 256; off <<= 1){
        int a = 0;
        if (t >= off) a = ts[t - off];
        __syncthreads();
        ts[t] += a;
        __syncthreads();
    }
    int excl = ts[t] - total + bscan[blockIdx.x];
    #pragma unroll
    for (int k = 0; k < 4; k++){
        int i = base + k;
        if (i < N_NODES){ rowptr[i] = excl; rowcur[i] = excl; excl += v[k]; }
    }
}

__global__ void k_scatter(const int* __restrict__ src, const int* __restrict__ dst,
                          int* __restrict__ rowcur, int* __restrict__ ssrc){
    int i = blockIdx.x * blockDim.x + threadIdx.x;
    if (i < E_EDGES){
        int d = dst[i];
        int pos = atomicAdd(&rowcur[d], 1);
        ssrc[pos] = src[i];
    }
}

// pull-mean over packed-bf16 rows of 32 uints (128B). One wave per node, 4/block.
// One coalesced ssrc load per <=64-edge chunk, broadcast via shfl; half-wave per edge.
__device__ inline void gather_mean_128B(const uint32* __restrict__ tab,
                                        const int* __restrict__ ssrc,
                                        int beg, int c, int lane,
                                        float& ax, float& ay){
    int half = lane >> 5, p = lane & 31;
    ax = 0.f; ay = 0.f;
    for (int e0 = 0; e0 < c; e0 += 64){
        int rem = c - e0; if (rem > 64) rem = 64;
        int se = (lane < rem) ? ssrc[beg + e0 + lane] : 0;
        int e = 0;
        for (; e + 8 <= rem; e += 8){
            int s0 = __shfl(se, e + half, 64);
            int s1 = __shfl(se, e + 2 + half, 64);
            int s2 = __shfl(se, e + 4 + half, 64);
            int s3 = __shfl(se, e + 6 + half, 64);
            uint32 w0 = tab[(size_t)s0 * 32 + p];
            uint32 w1 = tab[(size_t)s1 * 32 + p];
            uint32 w2 = tab[(size_t)s2 * 32 + p];
            uint32 w3 = tab[(size_t)s3 * 32 + p];
            float2 v0 = unpackbf2(w0), v1 = unpackbf2(w1), v2 = unpackbf2(w2), v3 = unpackbf2(w3);
            ax += v0.x + v1.x + v2.x + v3.x;
            ay += v0.y + v1.y + v2.y + v3.y;
        }
        for (; e + 2 <= rem; e += 2){
            int s = __shfl(se, e + half, 64);
            float2 v = unpackbf2(tab[(size_t)s * 32 + p]);
            ax += v.x; ay += v.y;
        }
        if (e < rem){
            int s = __shfl(se, e, 64);
            if (half == 0){
                float2 v = unpackbf2(tab[(size_t)s * 32 + p]);
                ax += v.x; ay += v.y;
            }
        }
    }
    ax += __shfl_xor(ax, 32, 64);
    ay += __shfl_xor(ay, 32, 64);
}

// mean1 = mean(x[src]) in bf16-packed form
__global__ void k_gather1(const uint32* __restrict__ xb, const int* __restrict__ ssrc,
                          const int* __restrict__ rowptr, const int* __restrict__ cnt,
                          uint32* __restrict__ mean1b){
    int g = threadIdx.x >> 6, lane = threadIdx.x & 63;
    int n = blockIdx.x * 4 + g;
    int beg = rowptr[n], c = cnt[n];
    float ax, ay;
    gather_mean_128B(xb, ssrc, beg, c, lane, ax, ay);
    float inv = 1.f / fmaxf((float)c, 1.f);
    if (lane < 32) mean1b[(size_t)n * 32 + lane] = packbf2(ax * inv, ay * inv);
}

// MFMA dense: h1 = relu([mean1|x]@wt1 + b1); [v|r2] = h1@wt2 (+b2 on r2 half)
__global__ __launch_bounds__(256) void k_dense1(
    const uint32* __restrict__ mean1b, const uint32* __restrict__ xb,
    const ushort* __restrict__ wt1g, const ushort* __restrict__ wt2g,
    const float* __restrict__ b1, const float* __restrict__ b2,
    ushort* __restrict__ vh, float* __restrict__ r2f){
    __shared__ ushort at[16 * AT_STRIDE];
    __shared__ ushort at2[16 * AT_STRIDE];
    int t = threadIdx.x;
    int nb0 = blockIdx.x * 16;
    {   // fill A-tile: node m, 64 uints (mean 32 | xb 32)
        int m = t >> 4;
        int q = (t & 15) * 4;
        size_t node = nb0 + m;
        uint4 val;
        if (q < 32) val = *(const uint4*)&mean1b[node * 32 + q];
        else        val = *(const uint4*)&xb[node * 32 + (q - 32)];
        *(uint4*)((uint32*)at + (m * (AT_STRIDE / 2) + q)) = val;
    }
    __syncthreads();
    int lane = t & 63, wave = t >> 6;
    int cidx = lane & 15, quad = lane >> 4;
    int nbA = wave * 32, nbB = wave * 32 + 16;
    float4v acc0 = {0.f,0.f,0.f,0.f}, acc1 = {0.f,0.f,0.f,0.f};
    #pragma unroll
    for (int s = 0; s < 4; s++){
        short8 a  = *(short8*)(at + (cidx * AT_STRIDE + s * 32 + quad * 8));
        short8 bA = *(const short8*)(wt1g + ((nbA + cidx) * 128 + s * 32 + quad * 8));
        short8 bB = *(const short8*)(wt1g + ((nbB + cidx) * 128 + s * 32 + quad * 8));
        acc0 = __builtin_amdgcn_mfma_f32_16x16x32_bf16(a, bA, acc0, 0, 0, 0);
        acc1 = __builtin_amdgcn_mfma_f32_16x16x32_bf16(a, bB, acc1, 0, 0, 0);
    }
    float b1A = b1[nbA + cidx], b1B = b1[nbB + cidx];
    #pragma unroll
    for (int i = 0; i < 4; i++){
        int row = quad * 4 + i;
        at2[row * AT_STRIDE + nbA + cidx] = (ushort)bf16rn(fmaxf(acc0[i] + b1A, 0.f));
        at2[row * AT_STRIDE + nbB + cidx] = (ushort)bf16rn(fmaxf(acc1[i] + b1B, 0.f));
    }
    __syncthreads();
    float4v c0 = {0.f,0.f,0.f,0.f}, c1 = {0.f,0.f,0.f,0.f};
    #pragma unroll
    for (int s = 0; s < 4; s++){
        short8 a  = *(short8*)(at2 + (cidx * AT_STRIDE + s * 32 + quad * 8));
        short8 bA = *(const short8*)(wt2g + ((nbA + cidx) * 128 + s * 32 + quad * 8));
        short8 bB = *(const short8*)(wt2g + ((nbB + cidx) * 128 + s * 32 + quad * 8));
        c0 = __builtin_amdgcn_mfma_f32_16x16x32_bf16(a, bA, c0, 0, 0, 0);
        c1 = __builtin_amdgcn_mfma_f32_16x16x32_bf16(a, bB, c1, 0, 0, 0);
    }
    #pragma unroll
    for (int i = 0; i < 4; i++){
        int row = quad * 4 + i;
        size_t node = nb0 + row;
        int colA = nbA + cidx;
        if (colA < 64) vh[node * 64 + colA] = (ushort)bf16rn(c0[i]);
        else           r2f[node * 64 + (colA - 64)] = c0[i] + b2[colA - 64];
        int colB = nbB + cidx;
        if (colB < 64) vh[node * 64 + colB] = (ushort)bf16rn(c1[i]);
        else           r2f[node * 64 + (colB - 64)] = c1[i] + b2[colB - 64];
    }
}

// mean(v[src]) + r2 -> h2 (relu), attention logit. One wave per node, 4/block.
__global__ void k_gather2(const float* __restrict__ x, const uint32* __restrict__ vb,
                          const int* __restrict__ ssrc, const int* __restrict__ rowptr,
                          const int* __restrict__ cnt, const float* __restrict__ r2f,
                          const float* __restrict__ Wa, const float* __restrict__ ba,
                          const float* __restrict__ ctx,
                          float* __restrict__ h2, float* __restrict__ wlogit){
    __shared__ float sh2[4][64];
    int g = threadIdx.x >> 6, lane = threadIdx.x & 63;
    int n = blockIdx.x * 4 + g;
    int beg = rowptr[n], c = cnt[n];
    float ax, ay;
    gather_mean_128B(vb, ssrc, beg, c, lane, ax, ay);
    float inv = 1.f / fmaxf((float)c, 1.f);
    int p = lane & 31;
    if (lane < 32){
        float2 rr = *(const float2*)&r2f[(size_t)n * 64 + 2 * p];
        float h2x = fmaxf(ax * inv + rr.x, 0.f);
        float h2y = fmaxf(ay * inv + rr.y, 0.f);
        sh2[g][2 * p] = h2x;
        sh2[g][2 * p + 1] = h2y;
        float2 st; st.x = h2x; st.y = h2y;
        *(float2*)&h2[(size_t)n * 64 + 2 * p] = st;
    }
    __syncthreads();
    float pa = 0.f;
    if (lane < ATT){
        float s = ba[lane];
        #pragma unroll 8
        for (int j = 0; j < 64; j++) s += sh2[g][j] * Wa[j * ATT + lane];
        pa = tanhf(s) * ctx[lane];
    }
    #pragma unroll
    for (int off = 16; off >= 1; off >>= 1) pa += __shfl_down(pa, off, 64);
    if (lane == 0) wlogit[n] = pa + x[(size_t)n * 64 + 63] * 0.4f;
}

__global__ void k_max(const float* __restrict__ wlogit, unsigned* __restrict__ maxu){
    float m = -INFINITY;
    for (size_t i = (size_t)blockIdx.x * blockDim.x + threadIdx.x; i < N_NODES; i += (size_t)gridDim.x * blockDim.x)
        m = fmaxf(m, wlogit[i]);
    #pragma unroll
    for (int off = 32; off >= 1; off >>= 1) m = fmaxf(m, __shfl_down(m, off, 64));
    __shared__ float sm[4];
    if ((threadIdx.x & 63) == 0) sm[threadIdx.x >> 6] = m;
    __syncthreads();
    if (threadIdx.x == 0){
        float mm = fmaxf(fmaxf(sm[0], sm[1]), fmaxf(sm[2], sm[3]));
        atomicMax(maxu, f2o(mm));
    }
}

__global__ void k_pool(const float* __restrict__ h2, const float* __restrict__ wlogit,
                       const unsigned* __restrict__ maxu, float* __restrict__ pooled, float* __restrict__ Z){
    float mv = o2f(*maxu);
    int lane = threadIdx.x & 63;
    int row  = threadIdx.x >> 6;
    float pacc = 0.f, zacc = 0.f;
    for (size_t n = (size_t)blockIdx.x * 4 + row; n < N_NODES; n += (size_t)gridDim.x * 4){
        float e = expf(wlogit[n] - mv);
        pacc += h2[n * 64 + lane] * e;
        zacc += e;
    }
    __shared__ float sp[4][64];
    sp[row][lane] = pacc;
    __syncthreads();
    if (threadIdx.x < 64){
        float s = sp[0][threadIdx.x] + sp[1][threadIdx.x] + sp[2][threadIdx.x] + sp[3][threadIdx.x];
        atomicAdd(&pooled[threadIdx.x], s);
    }
    if (lane == 0) atomicAdd(Z, zacc);
}

__global__ void k_final(const float* __restrict__ pooled, const float* __restrict__ Z,
                        const float* __restrict__ Wc1, const float* __restrict__ bc1,
                        const float* __restrict__ Wc2, const float* __restrict__ bc2,
                        float* __restrict__ out){
    __shared__ float sp[64], sz[32];
    int t = threadIdx.x;
    float scale = 1.0f / ((*Z) * (float)N_NODES);
    sp[t] = pooled[t] * scale;
    __syncthreads();
    if (t < 32){
        float s = bc1[t];
        #pragma unroll 8
        for (int j = 0; j < 64; j++) s += sp[j] * Wc1[j * 32 + t];
        sz[t] = fmaxf(s, 0.f);
    }
    __syncthreads();
    if (t == 0){
        float s = bc2[0];
        #pragma unroll
        for (int i = 0; i < 32; i++) s += sz[i] * Wc2[i];
        out[0] = 1.0f / (1.0f + expf(-s));
    }
}

extern "C" void kernel_launch(void* const* d_in, const int* in_sizes, int n_in,
                              void* d_out, int out_size, void* d_ws, size_t ws_size,
                              hipStream_t stream) {
    const float* x   = (const float*)d_in[0];
    const int*   ei  = (const int*)d_in[1];
    const int*   src = ei;
    const int*   dst = ei + E_EDGES;
    const float* W1l = (const float*)d_in[2];
    const float* W1r = (const float*)d_in[3];
    const float* b1  = (const float*)d_in[4];
    const float* W2l = (const float*)d_in[5];
    const float* W2r = (const float*)d_in[6];
    const float* b2  = (const float*)d_in[7];
    const float* Wa  = (const float*)d_in[8];
    const float* ba  = (const float*)d_in[9];
    const float* ctx = (const float*)d_in[10];
    const float* Wc1 = (const float*)d_in[11];
    const float* bc1 = (const float*)d_in[12];
    const float* Wc2 = (const float*)d_in[13];
    const float* bc2 = (const float*)d_in[14];

    char* p = (char*)d_ws;
    int* cnt    = (int*)p;                 p += (size_t)N_NODES * 4;
    int* rowptr = (int*)p;                 p += (size_t)N_NODES * 4;
    int* rowcur = (int*)p;                 p += (size_t)N_NODES * 4;
    int* bsum   = (int*)p;                 p += 128 * 4;
    int* bscan  = (int*)p;                 p += 128 * 4;
    int* ssrc   = (int*)p;                 p += (size_t)E_EDGES * 4;
    uint32* xb  = (uint32*)p;              p += (size_t)N_NODES * 32 * 4;
    uint32* mean1b = (uint32*)p;           p += (size_t)N_NODES * 32 * 4;
    ushort* vh  = (ushort*)p;              p += (size_t)N_NODES * 64 * 2;
    float* r2f  = (float*)p;               p += (size_t)N_NODES * 64 * 4;
    float* h2   = (float*)p;               p += (size_t)N_NODES * 64 * 4;
    float* wlogit = (float*)p;             p += (size_t)N_NODES * 4;
    ushort* wt1g = (ushort*)p;             p += 128 * 128 * 2;
    ushort* wt2g = (ushort*)p;             p += 128 * 128 * 2;
    float* pooled = (float*)p;             p += 64 * 4;
    float* Zp     = (float*)p;             p += 4;
    unsigned* maxu = (unsigned*)p;

    hipMemsetAsync(cnt, 0, (size_t)N_NODES * 4, stream);
    k_init<<<1, 128, 0, stream>>>(pooled, Zp, maxu);

    k_xcast<<<(N_NODES * 32 + 255) / 256, 256, 0, stream>>>(x, xb);
    k_prep<<<2, 256, 0, stream>>>(W1l, W1r, W2l, W2r, wt1g, wt2g);
    k_hist<<<(E_EDGES + 255) / 256, 256, 0, stream>>>(dst, cnt);
    k_scan1<<<NB_SCAN, 256, 0, stream>>>(cnt, bsum);
    k_scan2<<<1, 128, 0, stream>>>(bsum, bscan);
    k_scan3<<<NB_SCAN, 256, 0, stream>>>(cnt, bscan, rowptr, rowcur);
    k_scatter<<<(E_EDGES + 255) / 256, 256, 0, stream>>>(src, dst, rowcur, ssrc);

    k_gather1<<<N_NODES / 4, 256, 0, stream>>>(xb, ssrc, rowptr, cnt, mean1b);
    k_dense1<<<N_NODES / 16, 256, 0, stream>>>(mean1b, xb, wt1g, wt2g, b1, b2, vh, r2f);
    k_gather2<<<N_NODES / 4, 256, 0, stream>>>(x, (const uint32*)vh, ssrc, rowptr, cnt,
                                               r2f, Wa, ba, ctx, h2, wlogit);

    k_max<<<512, 256, 0, stream>>>(wlogit, maxu);
    k_pool<<<1024, 256, 0, stream>>>(h2, wlogit, maxu, pooled, Zp);
    k_final<<<1, 64, 0, stream>>>(pooled, Zp, Wc1, bc1, Wc2, bc2, (float*)d_out);
}

// Round 5
// 515.390 us; speedup vs baseline: 1.9432x; 1.1104x over previous
//
#include <hip/hip_runtime.h>
#include <math.h>

#define N_NODES 100000
#define E_EDGES 1600000
#define D_IN 64
#define HID1 128
#define HID2 64
#define ATT 32
#define CHUNK 1024
#define NB_SCAN ((N_NODES + CHUNK - 1) / CHUNK)   // 98
#define AT_STRIDE 136   // 128 + 8 bf16 pad: keeps ds_read_b128 16B-aligned, 2-way banks
#define NRANGE 8
#define RNODES (N_NODES / NRANGE)  // 12500

typedef unsigned int uint32;
typedef unsigned short ushort;
typedef __attribute__((ext_vector_type(8))) short short8;
typedef __attribute__((ext_vector_type(4))) float float4v;

__device__ inline unsigned f2o(float f){ unsigned u = __float_as_uint(f); return (u >> 31) ? ~u : (u | 0x80000000u); }
__device__ inline float o2f(unsigned u){ return (u >> 31) ? __uint_as_float(u & 0x7fffffffu) : __uint_as_float(~u); }

__device__ inline uint32 bf16rn(float f){ uint32 u = __float_as_uint(f); return (u + 0x7fffu + ((u >> 16) & 1u)) >> 16; }
__device__ inline uint32 packbf2(float a, float b){ return bf16rn(a) | (bf16rn(b) << 16); }
__device__ inline float2 unpackbf2(uint32 v){ float2 r; r.x = __uint_as_float(v << 16); r.y = __uint_as_float(v & 0xffff0000u); return r; }

__global__ void k_init(float* pooled, float* Z, unsigned* maxu){
    int t = threadIdx.x;
    if (t < 64) pooled[t] = 0.f;
    if (t == 64) *Z = 0.f;
    if (t == 65) *maxu = f2o(-INFINITY);
}

// x (N x 64 fp32) -> packed bf162 table (N x 32 uint)
__global__ void k_xcast(const float* __restrict__ x, uint32* __restrict__ xb){
    int i = blockIdx.x * 256 + threadIdx.x;
    if (i < N_NODES * 32){
        float2 v = ((const float2*)x)[i];
        xb[i] = packbf2(v.x, v.y);
    }
}

// one-time: build transposed bf16 weight tables wt[n][k] (128x128 each)
__global__ void k_prep(const float* __restrict__ W1l, const float* __restrict__ W1r,
                       const float* __restrict__ W2l, const float* __restrict__ W2r,
                       ushort* __restrict__ wt1g, ushort* __restrict__ wt2g){
    __shared__ ushort st[128 * 130];
    int t = threadIdx.x;
    int n = t & 127, kh = t >> 7;
    if (blockIdx.x == 0){
        for (int k0 = 0; k0 < 128; k0 += 2){
            int k = k0 + kh;
            float v = (k < 64) ? W1l[k * 128 + n] : W1r[(k - 64) * 128 + n];
            st[k * 130 + n] = (ushort)bf16rn(v);
        }
    } else {
        for (int k0 = 0; k0 < 128; k0 += 2){
            int k = k0 + kh;
            float v = (n < 64) ? W2l[k * 64 + n] : W2r[k * 64 + (n - 64)];
            st[k * 130 + n] = (ushort)bf16rn(v);
        }
    }
    __syncthreads();
    ushort* dstp = (blockIdx.x == 0) ? wt1g : wt2g;
    int kk = t & 127, nh = t >> 7;
    for (int n0 = 0; n0 < 128; n0 += 2){
        int nn = n0 + nh;
        dstp[nn * 128 + kk] = st[kk * 130 + nn];
    }
}

__global__ void k_hist(const int* __restrict__ dst, int* __restrict__ cnt){
    int i = blockIdx.x * blockDim.x + threadIdx.x;
    if (i < E_EDGES) atomicAdd(&cnt[dst[i]], 1);
}

__global__ void k_scan1(const int* __restrict__ cnt, int* __restrict__ bsum){
    int base = blockIdx.x * CHUNK + threadIdx.x * 4;
    int s = 0;
    #pragma unroll
    for (int k = 0; k < 4; k++){ int i = base + k; if (i < N_NODES) s += cnt[i]; }
    #pragma unroll
    for (int off = 32; off >= 1; off >>= 1) s += __shfl_down(s, off, 64);
    __shared__ int sm[4];
    if ((threadIdx.x & 63) == 0) sm[threadIdx.x >> 6] = s;
    __syncthreads();
    if (threadIdx.x == 0) bsum[blockIdx.x] = sm[0] + sm[1] + sm[2] + sm[3];
}

__global__ void k_scan2(const int* __restrict__ bsum, int* __restrict__ bscan){
    __shared__ int sb[NB_SCAN];
    int t = threadIdx.x;
    if (t < NB_SCAN) sb[t] = bsum[t];
    __syncthreads();
    if (t == 0){ int run = 0; for (int i = 0; i < NB_SCAN; i++){ int v = sb[i]; sb[i] = run; run += v; } }
    __syncthreads();
    if (t < NB_SCAN) bscan[t] = sb[t];
}

__global__ void k_scan3(const int* __restrict__ cnt, const int* __restrict__ bscan,
                        int* __restrict__ rowptr, int* __restrict__ rowcur){
    __shared__ int ts[256];
    int t = threadIdx.x;
    int base = blockIdx.x * CHUNK + t * 4;
    int v[4]; int s = 0;
    #pragma unroll
    for (int k = 0; k < 4; k++){ int i = base + k; v[k] = (i < N_NODES) ? cnt[i] : 0; s += v[k]; }
    ts[t] = s;
    __syncthreads();
    int total = s;
    for (int off = 1; off < 256; off <<= 1){
        int a = 0;
        if (t >= off) a = ts[t - off];
        __syncthreads();
        ts[t] += a;
        __syncthreads();
    }
    int excl = ts[t] - total + bscan[blockIdx.x];
    #pragma unroll
    for (int k = 0; k < 4; k++){
        int i = base + k;
        if (i < N_NODES){ rowptr[i] = excl; rowcur[i] = excl; excl += v[k]; }
    }
}

// dst-range-partitioned scatter: group g = blockIdx&7 handles dst in [g*RNODES,(g+1)*RNODES).
// Each group's writes land in one contiguous ~0.8MB slice of ssrc -> lines fill in one L2.
__global__ void k_scatter(const int* __restrict__ src, const int* __restrict__ dst,
                          int* __restrict__ rowcur, int* __restrict__ ssrc){
    int range = blockIdx.x & (NRANGE - 1);
    int blk   = blockIdx.x >> 3;
    int lo = range * RNODES, hi = lo + RNODES;
    int stride = (gridDim.x >> 3) * blockDim.x;
    for (int i = blk * blockDim.x + threadIdx.x; i < E_EDGES; i += stride){
        int d = dst[i];
        if (d >= lo && d < hi){
            int pos = atomicAdd(&rowcur[d], 1);
            ssrc[pos] = src[i];
        }
    }
}

// pull-mean over packed-bf16 rows of 32 uints (128B). One wave per node, 4/block.
__device__ inline void gather_mean_128B(const uint32* __restrict__ tab,
                                        const int* __restrict__ ssrc,
                                        int beg, int c, int lane,
                                        float& ax, float& ay){
    int half = lane >> 5, p = lane & 31;
    ax = 0.f; ay = 0.f;
    for (int e0 = 0; e0 < c; e0 += 64){
        int rem = c - e0; if (rem > 64) rem = 64;
        int se = (lane < rem) ? ssrc[beg + e0 + lane] : 0;
        int e = 0;
        for (; e + 8 <= rem; e += 8){
            int s0 = __shfl(se, e + half, 64);
            int s1 = __shfl(se, e + 2 + half, 64);
            int s2 = __shfl(se, e + 4 + half, 64);
            int s3 = __shfl(se, e + 6 + half, 64);
            uint32 w0 = tab[(size_t)s0 * 32 + p];
            uint32 w1 = tab[(size_t)s1 * 32 + p];
            uint32 w2 = tab[(size_t)s2 * 32 + p];
            uint32 w3 = tab[(size_t)s3 * 32 + p];
            float2 v0 = unpackbf2(w0), v1 = unpackbf2(w1), v2 = unpackbf2(w2), v3 = unpackbf2(w3);
            ax += v0.x + v1.x + v2.x + v3.x;
            ay += v0.y + v1.y + v2.y + v3.y;
        }
        for (; e + 2 <= rem; e += 2){
            int s = __shfl(se, e + half, 64);
            float2 v = unpackbf2(tab[(size_t)s * 32 + p]);
            ax += v.x; ay += v.y;
        }
        if (e < rem){
            int s = __shfl(se, e, 64);
            if (half == 0){
                float2 v = unpackbf2(tab[(size_t)s * 32 + p]);
                ax += v.x; ay += v.y;
            }
        }
    }
    ax += __shfl_xor(ax, 32, 64);
    ay += __shfl_xor(ay, 32, 64);
}

__global__ void k_gather1(const uint32* __restrict__ xb, const int* __restrict__ ssrc,
                          const int* __restrict__ rowptr, const int* __restrict__ cnt,
                          uint32* __restrict__ mean1b){
    int g = threadIdx.x >> 6, lane = threadIdx.x & 63;
    int n = blockIdx.x * 4 + g;
    int beg = rowptr[n], c = cnt[n];
    float ax, ay;
    gather_mean_128B(xb, ssrc, beg, c, lane, ax, ay);
    float inv = 1.f / fmaxf((float)c, 1.f);
    if (lane < 32) mean1b[(size_t)n * 32 + lane] = packbf2(ax * inv, ay * inv);
}

// MFMA dense: h1 = relu([mean1|x]@wt1 + b1); [v|r2] = h1@wt2 (+b2 on r2 half)
__global__ __launch_bounds__(256) void k_dense1(
    const uint32* __restrict__ mean1b, const uint32* __restrict__ xb,
    const ushort* __restrict__ wt1g, const ushort* __restrict__ wt2g,
    const float* __restrict__ b1, const float* __restrict__ b2,
    ushort* __restrict__ vh, float* __restrict__ r2f){
    __shared__ ushort at[16 * AT_STRIDE];
    __shared__ ushort at2[16 * AT_STRIDE];
    int t = threadIdx.x;
    int nb0 = blockIdx.x * 16;
    {
        int m = t >> 4;
        int q = (t & 15) * 4;
        size_t node = nb0 + m;
        uint4 val;
        if (q < 32) val = *(const uint4*)&mean1b[node * 32 + q];
        else        val = *(const uint4*)&xb[node * 32 + (q - 32)];
        *(uint4*)((uint32*)at + (m * (AT_STRIDE / 2) + q)) = val;
    }
    __syncthreads();
    int lane = t & 63, wave = t >> 6;
    int cidx = lane & 15, quad = lane >> 4;
    int nbA = wave * 32, nbB = wave * 32 + 16;
    float4v acc0 = {0.f,0.f,0.f,0.f}, acc1 = {0.f,0.f,0.f,0.f};
    #pragma unroll
    for (int s = 0; s < 4; s++){
        short8 a  = *(short8*)(at + (cidx * AT_STRIDE + s * 32 + quad * 8));
        short8 bA = *(const short8*)(wt1g + ((nbA + cidx) * 128 + s * 32 + quad * 8));
        short8 bB = *(const short8*)(wt1g + ((nbB + cidx) * 128 + s * 32 + quad * 8));
        acc0 = __builtin_amdgcn_mfma_f32_16x16x32_bf16(a, bA, acc0, 0, 0, 0);
        acc1 = __builtin_amdgcn_mfma_f32_16x16x32_bf16(a, bB, acc1, 0, 0, 0);
    }
    float b1A = b1[nbA + cidx], b1B = b1[nbB + cidx];
    #pragma unroll
    for (int i = 0; i < 4; i++){
        int row = quad * 4 + i;
        at2[row * AT_STRIDE + nbA + cidx] = (ushort)bf16rn(fmaxf(acc0[i] + b1A, 0.f));
        at2[row * AT_STRIDE + nbB + cidx] = (ushort)bf16rn(fmaxf(acc1[i] + b1B, 0.f));
    }
    __syncthreads();
    float4v c0 = {0.f,0.f,0.f,0.f}, c1 = {0.f,0.f,0.f,0.f};
    #pragma unroll
    for (int s = 0; s < 4; s++){
        short8 a  = *(short8*)(at2 + (cidx * AT_STRIDE + s * 32 + quad * 8));
        short8 bA = *(const short8*)(wt2g + ((nbA + cidx) * 128 + s * 32 + quad * 8));
        short8 bB = *(const short8*)(wt2g + ((nbB + cidx) * 128 + s * 32 + quad * 8));
        c0 = __builtin_amdgcn_mfma_f32_16x16x32_bf16(a, bA, c0, 0, 0, 0);
        c1 = __builtin_amdgcn_mfma_f32_16x16x32_bf16(a, bB, c1, 0, 0, 0);
    }
    #pragma unroll
    for (int i = 0; i < 4; i++){
        int row = quad * 4 + i;
        size_t node = nb0 + row;
        int colA = nbA + cidx;
        if (colA < 64) vh[node * 64 + colA] = (ushort)bf16rn(c0[i]);
        else           r2f[node * 64 + (colA - 64)] = c0[i] + b2[colA - 64];
        int colB = nbB + cidx;
        if (colB < 64) vh[node * 64 + colB] = (ushort)bf16rn(c1[i]);
        else           r2f[node * 64 + (colB - 64)] = c1[i] + b2[colB - 64];
    }
}

__global__ void k_gather2(const float* __restrict__ x, const uint32* __restrict__ vb,
                          const int* __restrict__ ssrc, const int* __restrict__ rowptr,
                          const int* __restrict__ cnt, const float* __restrict__ r2f,
                          const float* __restrict__ Wa, const float* __restrict__ ba,
                          const float* __restrict__ ctx,
                          float* __restrict__ h2, float* __restrict__ wlogit){
    __shared__ float sh2[4][64];
    int g = threadIdx.x >> 6, lane = threadIdx.x & 63;
    int n = blockIdx.x * 4 + g;
    int beg = rowptr[n], c = cnt[n];
    float ax, ay;
    gather_mean_128B(vb, ssrc, beg, c, lane, ax, ay);
    float inv = 1.f / fmaxf((float)c, 1.f);
    int p = lane & 31;
    if (lane < 32){
        float2 rr = *(const float2*)&r2f[(size_t)n * 64 + 2 * p];
        float h2x = fmaxf(ax * inv + rr.x, 0.f);
        float h2y = fmaxf(ay * inv + rr.y, 0.f);
        sh2[g][2 * p] = h2x;
        sh2[g][2 * p + 1] = h2y;
        float2 st; st.x = h2x; st.y = h2y;
        *(float2*)&h2[(size_t)n * 64 + 2 * p] = st;
    }
    __syncthreads();
    float pa = 0.f;
    if (lane < ATT){
        float s = ba[lane];
        #pragma unroll 8
        for (int j = 0; j < 64; j++) s += sh2[g][j] * Wa[j * ATT + lane];
        pa = tanhf(s) * ctx[lane];
    }
    #pragma unroll
    for (int off = 16; off >= 1; off >>= 1) pa += __shfl_down(pa, off, 64);
    if (lane == 0) wlogit[n] = pa + x[(size_t)n * 64 + 63] * 0.4f;
}

__global__ void k_max(const float* __restrict__ wlogit, unsigned* __restrict__ maxu){
    float m = -INFINITY;
    for (size_t i = (size_t)blockIdx.x * blockDim.x + threadIdx.x; i < N_NODES; i += (size_t)gridDim.x * blockDim.x)
        m = fmaxf(m, wlogit[i]);
    #pragma unroll
    for (int off = 32; off >= 1; off >>= 1) m = fmaxf(m, __shfl_down(m, off, 64));
    __shared__ float sm[4];
    if ((threadIdx.x & 63) == 0) sm[threadIdx.x >> 6] = m;
    __syncthreads();
    if (threadIdx.x == 0){
        float mm = fmaxf(fmaxf(sm[0], sm[1]), fmaxf(sm[2], sm[3]));
        atomicMax(maxu, f2o(mm));
    }
}

__global__ void k_pool(const float* __restrict__ h2, const float* __restrict__ wlogit,
                       const unsigned* __restrict__ maxu, float* __restrict__ pooled, float* __restrict__ Z){
    float mv = o2f(*maxu);
    int lane = threadIdx.x & 63;
    int row  = threadIdx.x >> 6;
    float pacc = 0.f, zacc = 0.f;
    for (size_t n = (size_t)blockIdx.x * 4 + row; n < N_NODES; n += (size_t)gridDim.x * 4){
        float e = expf(wlogit[n] - mv);
        pacc += h2[n * 64 + lane] * e;
        zacc += e;
    }
    __shared__ float sp[4][64];
    sp[row][lane] = pacc;
    __syncthreads();
    if (threadIdx.x < 64){
        float s = sp[0][threadIdx.x] + sp[1][threadIdx.x] + sp[2][threadIdx.x] + sp[3][threadIdx.x];
        atomicAdd(&pooled[threadIdx.x], s);
    }
    if (lane == 0) atomicAdd(Z, zacc);
}

__global__ void k_final(const float* __restrict__ pooled, const float* __restrict__ Z,
                        const float* __restrict__ Wc1, const float* __restrict__ bc1,
                        const float* __restrict__ Wc2, const float* __restrict__ bc2,
                        float* __restrict__ out){
    __shared__ float sp[64], sz[32];
    int t = threadIdx.x;
    float scale = 1.0f / ((*Z) * (float)N_NODES);
    sp[t] = pooled[t] * scale;
    __syncthreads();
    if (t < 32){
        float s = bc1[t];
        #pragma unroll 8
        for (int j = 0; j < 64; j++) s += sp[j] * Wc1[j * 32 + t];
        sz[t] = fmaxf(s, 0.f);
    }
    __syncthreads();
    if (t == 0){
        float s = bc2[0];
        #pragma unroll
        for (int i = 0; i < 32; i++) s += sz[i] * Wc2[i];
        out[0] = 1.0f / (1.0f + expf(-s));
    }
}

extern "C" void kernel_launch(void* const* d_in, const int* in_sizes, int n_in,
                              void* d_out, int out_size, void* d_ws, size_t ws_size,
                              hipStream_t stream) {
    const float* x   = (const float*)d_in[0];
    const int*   ei  = (const int*)d_in[1];
    const int*   src = ei;
    const int*   dst = ei + E_EDGES;
    const float* W1l = (const float*)d_in[2];
    const float* W1r = (const float*)d_in[3];
    const float* b1  = (const float*)d_in[4];
    const float* W2l = (const float*)d_in[5];
    const float* W2r = (const float*)d_in[6];
    const float* b2  = (const float*)d_in[7];
    const float* Wa  = (const float*)d_in[8];
    const float* ba  = (const float*)d_in[9];
    const float* ctx = (const float*)d_in[10];
    const float* Wc1 = (const float*)d_in[11];
    const float* bc1 = (const float*)d_in[12];
    const float* Wc2 = (const float*)d_in[13];
    const float* bc2 = (const float*)d_in[14];

    char* p = (char*)d_ws;
    int* cnt    = (int*)p;                 p += (size_t)N_NODES * 4;
    int* rowptr = (int*)p;                 p += (size_t)N_NODES * 4;
    int* rowcur = (int*)p;                 p += (size_t)N_NODES * 4;
    int* bsum   = (int*)p;                 p += 128 * 4;
    int* bscan  = (int*)p;                 p += 128 * 4;
    int* ssrc   = (int*)p;                 p += (size_t)E_EDGES * 4;
    uint32* xb  = (uint32*)p;              p += (size_t)N_NODES * 32 * 4;
    uint32* mean1b = (uint32*)p;           p += (size_t)N_NODES * 32 * 4;
    ushort* vh  = (ushort*)p;              p += (size_t)N_NODES * 64 * 2;
    float* r2f  = (float*)p;               p += (size_t)N_NODES * 64 * 4;
    float* h2   = (float*)p;               p += (size_t)N_NODES * 64 * 4;
    float* wlogit = (float*)p;             p += (size_t)N_NODES * 4;
    ushort* wt1g = (ushort*)p;             p += 128 * 128 * 2;
    ushort* wt2g = (ushort*)p;             p += 128 * 128 * 2;
    float* pooled = (float*)p;             p += 64 * 4;
    float* Zp     = (float*)p;             p += 4;
    unsigned* maxu = (unsigned*)p;

    hipMemsetAsync(cnt, 0, (size_t)N_NODES * 4, stream);
    k_init<<<1, 128, 0, stream>>>(pooled, Zp, maxu);

    k_xcast<<<(N_NODES * 32 + 255) / 256, 256, 0, stream>>>(x, xb);
    k_prep<<<2, 256, 0, stream>>>(W1l, W1r, W2l, W2r, wt1g, wt2g);
    k_hist<<<(E_EDGES + 255) / 256, 256, 0, stream>>>(dst, cnt);
    k_scan1<<<NB_SCAN, 256, 0, stream>>>(cnt, bsum);
    k_scan2<<<1, 128, 0, stream>>>(bsum, bscan);
    k_scan3<<<NB_SCAN, 256, 0, stream>>>(cnt, bscan, rowptr, rowcur);
    k_scatter<<<1024, 256, 0, stream>>>(src, dst, rowcur, ssrc);

    k_gather1<<<N_NODES / 4, 256, 0, stream>>>(xb, ssrc, rowptr, cnt, mean1b);
    k_dense1<<<N_NODES / 16, 256, 0, stream>>>(mean1b, xb, wt1g, wt2g, b1, b2, vh, r2f);
    k_gather2<<<N_NODES / 4, 256, 0, stream>>>(x, (const uint32*)vh, ssrc, rowptr, cnt,
                                               r2f, Wa, ba, ctx, h2, wlogit);

    k_max<<<512, 256, 0, stream>>>(wlogit, maxu);
    k_pool<<<1024, 256, 0, stream>>>(h2, wlogit, maxu, pooled, Zp);
    k_final<<<1, 64, 0, stream>>>(pooled, Zp, Wc1, bc1, Wc2, bc2, (float*)d_out);
}

// Round 6
// 511.502 us; speedup vs baseline: 1.9579x; 1.0076x over previous
//
#include <hip/hip_runtime.h>
#include <math.h>

#define N_NODES 100000
#define E_EDGES 1600000
#define D_IN 64
#define HID1 128
#define HID2 64
#define ATT 32
#define CHUNK 1024
#define NB_SCAN ((N_NODES + CHUNK - 1) / CHUNK)   // 98
#define AT_STRIDE 136   // 128 + 8 bf16 pad: keeps ds_read_b128 16B-aligned, 2-way banks
#define NRANGE 8
#define RNODES (N_NODES / NRANGE)  // 12500

typedef unsigned int uint32;
typedef unsigned short ushort;
typedef __attribute__((ext_vector_type(8))) short short8;
typedef __attribute__((ext_vector_type(4))) float float4v;

__device__ inline unsigned f2o(float f){ unsigned u = __float_as_uint(f); return (u >> 31) ? ~u : (u | 0x80000000u); }
__device__ inline float o2f(unsigned u){ return (u >> 31) ? __uint_as_float(u & 0x7fffffffu) : __uint_as_float(~u); }

__device__ inline uint32 bf16rn(float f){ uint32 u = __float_as_uint(f); return (u + 0x7fffu + ((u >> 16) & 1u)) >> 16; }
__device__ inline uint32 packbf2(float a, float b){ return bf16rn(a) | (bf16rn(b) << 16); }
__device__ inline float2 unpackbf2(uint32 v){ float2 r; r.x = __uint_as_float(v << 16); r.y = __uint_as_float(v & 0xffff0000u); return r; }

// ---- fp8 e4m3fn helpers (HW cvt on gfx950; exact SW fallback) ----
#if __has_builtin(__builtin_amdgcn_cvt_f32_fp8) && __has_builtin(__builtin_amdgcn_cvt_pk_fp8_f32)
#define HW_FP8 1
#endif

__device__ inline uint32 fp8_enc_sw(float f){
    float a = fabsf(f);
    uint32 s = (__float_as_uint(f) >> 24) & 0x80u;
    if (!(a >= 0.001953125f)) return s;            // |v| < 2^-9 -> signed zero
    if (a > 448.f) return s | 0x7Eu;               // clamp to max finite
    if (a < 0.015625f){                            // subnormal: m * 2^-9
        uint32 c = (uint32)rintf(a * 512.f);       // 0..8 (8 rolls into 0x08 = 2^-6, correct)
        return s | c;
    }
    int e; float m = frexpf(a, &e);                // a = m*2^e, m in [0.5,1)
    int E = e - 1;                                 // mant in [1,2)
    float mant = 2.f * m;
    uint32 mc = (uint32)rintf((mant - 1.f) * 8.f); // 0..8
    uint32 Ec = (uint32)(E + 7);
    if (mc == 8u){ mc = 0u; Ec += 1u; }
    if (Ec >= 16u || (Ec == 15u && mc > 6u)) return s | 0x7Eu;
    return s | (Ec << 3) | mc;
}

__device__ inline float fp8_dec_sw(uint32 c){
    uint32 s = (c & 0x80u) << 24;
    uint32 E = (c >> 3) & 0xFu, m = c & 7u;
    float v;
    if (E == 0) v = (float)m * 0.001953125f;
    else v = __uint_as_float(((E + 120u) << 23) | (m << 20));
    return __uint_as_float(__float_as_uint(v) | s);
}

__device__ inline uint32 enc4(float a, float b, float c, float d){
#ifdef HW_FP8
    int r = __builtin_amdgcn_cvt_pk_fp8_f32(a, b, 0, false);
    r = __builtin_amdgcn_cvt_pk_fp8_f32(c, d, r, true);
    return (uint32)r;
#else
    return fp8_enc_sw(a) | (fp8_enc_sw(b) << 8) | (fp8_enc_sw(c) << 16) | (fp8_enc_sw(d) << 24);
#endif
}

__device__ inline void dec4acc(uint32 w, float& a0, float& a1, float& a2, float& a3){
#ifdef HW_FP8
    a0 += __builtin_amdgcn_cvt_f32_fp8((int)w, 0);
    a1 += __builtin_amdgcn_cvt_f32_fp8((int)w, 1);
    a2 += __builtin_amdgcn_cvt_f32_fp8((int)w, 2);
    a3 += __builtin_amdgcn_cvt_f32_fp8((int)w, 3);
#else
    a0 += fp8_dec_sw(w & 0xffu);
    a1 += fp8_dec_sw((w >> 8) & 0xffu);
    a2 += fp8_dec_sw((w >> 16) & 0xffu);
    a3 += fp8_dec_sw(w >> 24);
#endif
}

__global__ void k_init(float* pooled, float* Z, unsigned* maxu){
    int t = threadIdx.x;
    if (t < 64) pooled[t] = 0.f;
    if (t == 64) *Z = 0.f;
    if (t == 65) *maxu = f2o(-INFINITY);
}

// x (N x 64 fp32) -> bf16-packed xb (N x 32 uint) AND fp8-packed xq (N x 16 uint)
__global__ void k_xcast(const float* __restrict__ x, uint32* __restrict__ xb, uint32* __restrict__ xq){
    int i = blockIdx.x * 256 + threadIdx.x;
    if (i < N_NODES * 16){
        float4 v = ((const float4*)x)[i];
        xb[2 * i]     = packbf2(v.x, v.y);
        xb[2 * i + 1] = packbf2(v.z, v.w);
        xq[i] = enc4(v.x, v.y, v.z, v.w);
    }
}

// vh (bf16 packed, N x 32 uint) -> vq (fp8 packed, N x 16 uint)
__global__ void k_vcast(const uint32* __restrict__ vh, uint32* __restrict__ vq){
    int i = blockIdx.x * 256 + threadIdx.x;
    if (i < N_NODES * 16){
        uint2 w = ((const uint2*)vh)[i];
        float2 v0 = unpackbf2(w.x), v1 = unpackbf2(w.y);
        vq[i] = enc4(v0.x, v0.y, v1.x, v1.y);
    }
}

// one-time: build transposed bf16 weight tables wt[n][k] (128x128 each)
__global__ void k_prep(const float* __restrict__ W1l, const float* __restrict__ W1r,
                       const float* __restrict__ W2l, const float* __restrict__ W2r,
                       ushort* __restrict__ wt1g, ushort* __restrict__ wt2g){
    __shared__ ushort st[128 * 130];
    int t = threadIdx.x;
    int n = t & 127, kh = t >> 7;
    if (blockIdx.x == 0){
        for (int k0 = 0; k0 < 128; k0 += 2){
            int k = k0 + kh;
            float v = (k < 64) ? W1l[k * 128 + n] : W1r[(k - 64) * 128 + n];
            st[k * 130 + n] = (ushort)bf16rn(v);
        }
    } else {
        for (int k0 = 0; k0 < 128; k0 += 2){
            int k = k0 + kh;
            float v = (n < 64) ? W2l[k * 64 + n] : W2r[k * 64 + (n - 64)];
            st[k * 130 + n] = (ushort)bf16rn(v);
        }
    }
    __syncthreads();
    ushort* dstp = (blockIdx.x == 0) ? wt1g : wt2g;
    int kk = t & 127, nh = t >> 7;
    for (int n0 = 0; n0 < 128; n0 += 2){
        int nn = n0 + nh;
        dstp[nn * 128 + kk] = st[kk * 130 + nn];
    }
}

__global__ void k_hist(const int* __restrict__ dst, int* __restrict__ cnt){
    int i = blockIdx.x * blockDim.x + threadIdx.x;
    if (i < E_EDGES) atomicAdd(&cnt[dst[i]], 1);
}

__global__ void k_scan1(const int* __restrict__ cnt, int* __restrict__ bsum){
    int base = blockIdx.x * CHUNK + threadIdx.x * 4;
    int s = 0;
    #pragma unroll
    for (int k = 0; k < 4; k++){ int i = base + k; if (i < N_NODES) s += cnt[i]; }
    #pragma unroll
    for (int off = 32; off >= 1; off >>= 1) s += __shfl_down(s, off, 64);
    __shared__ int sm[4];
    if ((threadIdx.x & 63) == 0) sm[threadIdx.x >> 6] = s;
    __syncthreads();
    if (threadIdx.x == 0) bsum[blockIdx.x] = sm[0] + sm[1] + sm[2] + sm[3];
}

__global__ void k_scan2(const int* __restrict__ bsum, int* __restrict__ bscan){
    __shared__ int sb[NB_SCAN];
    int t = threadIdx.x;
    if (t < NB_SCAN) sb[t] = bsum[t];
    __syncthreads();
    if (t == 0){ int run = 0; for (int i = 0; i < NB_SCAN; i++){ int v = sb[i]; sb[i] = run; run += v; } }
    __syncthreads();
    if (t < NB_SCAN) bscan[t] = sb[t];
}

__global__ void k_scan3(const int* __restrict__ cnt, const int* __restrict__ bscan,
                        int* __restrict__ rowptr, int* __restrict__ rowcur){
    __shared__ int ts[256];
    int t = threadIdx.x;
    int base = blockIdx.x * CHUNK + t * 4;
    int v[4]; int s = 0;
    #pragma unroll
    for (int k = 0; k < 4; k++){ int i = base + k; v[k] = (i < N_NODES) ? cnt[i] : 0; s += v[k]; }
    ts[t] = s;
    __syncthreads();
    int total = s;
    for (int off = 1; off < 256; off <<= 1){
        int a = 0;
        if (t >= off) a = ts[t - off];
        __syncthreads();
        ts[t] += a;
        __syncthreads();
    }
    int excl = ts[t] - total + bscan[blockIdx.x];
    #pragma unroll
    for (int k = 0; k < 4; k++){
        int i = base + k;
        if (i < N_NODES){ rowptr[i] = excl; rowcur[i] = excl; excl += v[k]; }
    }
}

// dst-range-partitioned scatter (writes land in one contiguous slice per group)
__global__ void k_scatter(const int* __restrict__ src, const int* __restrict__ dst,
                          int* __restrict__ rowcur, int* __restrict__ ssrc){
    int range = blockIdx.x & (NRANGE - 1);
    int blk   = blockIdx.x >> 3;
    int lo = range * RNODES, hi = lo + RNODES;
    int stride = (gridDim.x >> 3) * blockDim.x;
    for (int i = blk * blockDim.x + threadIdx.x; i < E_EDGES; i += stride){
        int d = dst[i];
        if (d >= lo && d < hi){
            int pos = atomicAdd(&rowcur[d], 1);
            ssrc[pos] = src[i];
        }
    }
}

// pull-mean over fp8 rows of 16 uints (64B). One wave per node; quarter-wave per edge.
// Lane p (0..15) accumulates dims 4p..4p+3 in a0..a3.
__device__ inline void gather_mean_fp8(const uint32* __restrict__ tab,
                                       const int* __restrict__ ssrc,
                                       int beg, int c, int lane,
                                       float& a0, float& a1, float& a2, float& a3){
    int q = lane >> 4, p = lane & 15;
    a0 = a1 = a2 = a3 = 0.f;
    for (int e0 = 0; e0 < c; e0 += 64){
        int rem = c - e0; if (rem > 64) rem = 64;
        int se = (lane < rem) ? ssrc[beg + e0 + lane] : 0;
        int e = 0;
        for (; e + 16 <= rem; e += 16){
            #pragma unroll
            for (int st = 0; st < 4; st++){
                int s = __shfl(se, e + st * 4 + q, 64);
                uint32 w = tab[(size_t)s * 16 + p];
                dec4acc(w, a0, a1, a2, a3);
            }
        }
        for (; e + 4 <= rem; e += 4){
            int s = __shfl(se, e + q, 64);
            uint32 w = tab[(size_t)s * 16 + p];
            dec4acc(w, a0, a1, a2, a3);
        }
        if (e < rem){
            int r = rem - e;
            int s = __shfl(se, e + (q < r ? q : 0), 64);
            if (q < r){
                uint32 w = tab[(size_t)s * 16 + p];
                dec4acc(w, a0, a1, a2, a3);
            }
        }
    }
    a0 += __shfl_xor(a0, 16, 64); a1 += __shfl_xor(a1, 16, 64);
    a2 += __shfl_xor(a2, 16, 64); a3 += __shfl_xor(a3, 16, 64);
    a0 += __shfl_xor(a0, 32, 64); a1 += __shfl_xor(a1, 32, 64);
    a2 += __shfl_xor(a2, 32, 64); a3 += __shfl_xor(a3, 32, 64);
}

__global__ void k_gather1(const uint32* __restrict__ xq, const int* __restrict__ ssrc,
                          const int* __restrict__ rowptr, const int* __restrict__ cnt,
                          uint32* __restrict__ mean1b){
    int g = threadIdx.x >> 6, lane = threadIdx.x & 63;
    int n = blockIdx.x * 4 + g;
    int beg = rowptr[n], c = cnt[n];
    float a0, a1, a2, a3;
    gather_mean_fp8(xq, ssrc, beg, c, lane, a0, a1, a2, a3);
    float inv = 1.f / fmaxf((float)c, 1.f);
    if (lane < 16){
        uint2 o;
        o.x = packbf2(a0 * inv, a1 * inv);
        o.y = packbf2(a2 * inv, a3 * inv);
        *(uint2*)&mean1b[(size_t)n * 32 + 2 * lane] = o;
    }
}

// MFMA dense: h1 = relu([mean1|x]@wt1 + b1); [v|r2] = h1@wt2 (+b2 on r2 half)
__global__ __launch_bounds__(256) void k_dense1(
    const uint32* __restrict__ mean1b, const uint32* __restrict__ xb,
    const ushort* __restrict__ wt1g, const ushort* __restrict__ wt2g,
    const float* __restrict__ b1, const float* __restrict__ b2,
    ushort* __restrict__ vh, float* __restrict__ r2f){
    __shared__ ushort at[16 * AT_STRIDE];
    __shared__ ushort at2[16 * AT_STRIDE];
    int t = threadIdx.x;
    int nb0 = blockIdx.x * 16;
    {
        int m = t >> 4;
        int q = (t & 15) * 4;
        size_t node = nb0 + m;
        uint4 val;
        if (q < 32) val = *(const uint4*)&mean1b[node * 32 + q];
        else        val = *(const uint4*)&xb[node * 32 + (q - 32)];
        *(uint4*)((uint32*)at + (m * (AT_STRIDE / 2) + q)) = val;
    }
    __syncthreads();
    int lane = t & 63, wave = t >> 6;
    int cidx = lane & 15, quad = lane >> 4;
    int nbA = wave * 32, nbB = wave * 32 + 16;
    float4v acc0 = {0.f,0.f,0.f,0.f}, acc1 = {0.f,0.f,0.f,0.f};
    #pragma unroll
    for (int s = 0; s < 4; s++){
        short8 a  = *(short8*)(at + (cidx * AT_STRIDE + s * 32 + quad * 8));
        short8 bA = *(const short8*)(wt1g + ((nbA + cidx) * 128 + s * 32 + quad * 8));
        short8 bB = *(const short8*)(wt1g + ((nbB + cidx) * 128 + s * 32 + quad * 8));
        acc0 = __builtin_amdgcn_mfma_f32_16x16x32_bf16(a, bA, acc0, 0, 0, 0);
        acc1 = __builtin_amdgcn_mfma_f32_16x16x32_bf16(a, bB, acc1, 0, 0, 0);
    }
    float b1A = b1[nbA + cidx], b1B = b1[nbB + cidx];
    #pragma unroll
    for (int i = 0; i < 4; i++){
        int row = quad * 4 + i;
        at2[row * AT_STRIDE + nbA + cidx] = (ushort)bf16rn(fmaxf(acc0[i] + b1A, 0.f));
        at2[row * AT_STRIDE + nbB + cidx] = (ushort)bf16rn(fmaxf(acc1[i] + b1B, 0.f));
    }
    __syncthreads();
    float4v c0 = {0.f,0.f,0.f,0.f}, c1 = {0.f,0.f,0.f,0.f};
    #pragma unroll
    for (int s = 0; s < 4; s++){
        short8 a  = *(short8*)(at2 + (cidx * AT_STRIDE + s * 32 + quad * 8));
        short8 bA = *(const short8*)(wt2g + ((nbA + cidx) * 128 + s * 32 + quad * 8));
        short8 bB = *(const short8*)(wt2g + ((nbB + cidx) * 128 + s * 32 + quad * 8));
        c0 = __builtin_amdgcn_mfma_f32_16x16x32_bf16(a, bA, c0, 0, 0, 0);
        c1 = __builtin_amdgcn_mfma_f32_16x16x32_bf16(a, bB, c1, 0, 0, 0);
    }
    #pragma unroll
    for (int i = 0; i < 4; i++){
        int row = quad * 4 + i;
        size_t node = nb0 + row;
        int colA = nbA + cidx;
        if (colA < 64) vh[node * 64 + colA] = (ushort)bf16rn(c0[i]);
        else           r2f[node * 64 + (colA - 64)] = c0[i] + b2[colA - 64];
        int colB = nbB + cidx;
        if (colB < 64) vh[node * 64 + colB] = (ushort)bf16rn(c1[i]);
        else           r2f[node * 64 + (colB - 64)] = c1[i] + b2[colB - 64];
    }
}

__global__ void k_gather2(const float* __restrict__ x, const uint32* __restrict__ vq,
                          const int* __restrict__ ssrc, const int* __restrict__ rowptr,
                          const int* __restrict__ cnt, const float* __restrict__ r2f,
                          const float* __restrict__ Wa, const float* __restrict__ ba,
                          const float* __restrict__ ctx,
                          float* __restrict__ h2, float* __restrict__ wlogit){
    __shared__ float sh2[4][64];
    int g = threadIdx.x >> 6, lane = threadIdx.x & 63;
    int n = blockIdx.x * 4 + g;
    int beg = rowptr[n], c = cnt[n];
    float a0, a1, a2, a3;
    gather_mean_fp8(vq, ssrc, beg, c, lane, a0, a1, a2, a3);
    float inv = 1.f / fmaxf((float)c, 1.f);
    if (lane < 16){
        float4 rr = *(const float4*)&r2f[(size_t)n * 64 + 4 * lane];
        float h0 = fmaxf(a0 * inv + rr.x, 0.f);
        float h1v = fmaxf(a1 * inv + rr.y, 0.f);
        float h2v = fmaxf(a2 * inv + rr.z, 0.f);
        float h3 = fmaxf(a3 * inv + rr.w, 0.f);
        sh2[g][4 * lane] = h0; sh2[g][4 * lane + 1] = h1v;
        sh2[g][4 * lane + 2] = h2v; sh2[g][4 * lane + 3] = h3;
        float4 st; st.x = h0; st.y = h1v; st.z = h2v; st.w = h3;
        *(float4*)&h2[(size_t)n * 64 + 4 * lane] = st;
    }
    __syncthreads();
    float pa = 0.f;
    if (lane < ATT){
        float s = ba[lane];
        #pragma unroll 8
        for (int j = 0; j < 64; j++) s += sh2[g][j] * Wa[j * ATT + lane];
        pa = tanhf(s) * ctx[lane];
    }
    #pragma unroll
    for (int off = 16; off >= 1; off >>= 1) pa += __shfl_down(pa, off, 64);
    if (lane == 0) wlogit[n] = pa + x[(size_t)n * 64 + 63] * 0.4f;
}

__global__ void k_max(const float* __restrict__ wlogit, unsigned* __restrict__ maxu){
    float m = -INFINITY;
    for (size_t i = (size_t)blockIdx.x * blockDim.x + threadIdx.x; i < N_NODES; i += (size_t)gridDim.x * blockDim.x)
        m = fmaxf(m, wlogit[i]);
    #pragma unroll
    for (int off = 32; off >= 1; off >>= 1) m = fmaxf(m, __shfl_down(m, off, 64));
    __shared__ float sm[4];
    if ((threadIdx.x & 63) == 0) sm[threadIdx.x >> 6] = m;
    __syncthreads();
    if (threadIdx.x == 0){
        float mm = fmaxf(fmaxf(sm[0], sm[1]), fmaxf(sm[2], sm[3]));
        atomicMax(maxu, f2o(mm));
    }
}

__global__ void k_pool(const float* __restrict__ h2, const float* __restrict__ wlogit,
                       const unsigned* __restrict__ maxu, float* __restrict__ pooled, float* __restrict__ Z){
    float mv = o2f(*maxu);
    int lane = threadIdx.x & 63;
    int row  = threadIdx.x >> 6;
    float pacc = 0.f, zacc = 0.f;
    for (size_t n = (size_t)blockIdx.x * 4 + row; n < N_NODES; n += (size_t)gridDim.x * 4){
        float e = expf(wlogit[n] - mv);
        pacc += h2[n * 64 + lane] * e;
        zacc += e;
    }
    __shared__ float sp[4][64];
    sp[row][lane] = pacc;
    __syncthreads();
    if (threadIdx.x < 64){
        float s = sp[0][threadIdx.x] + sp[1][threadIdx.x] + sp[2][threadIdx.x] + sp[3][threadIdx.x];
        atomicAdd(&pooled[threadIdx.x], s);
    }
    if (lane == 0) atomicAdd(Z, zacc);
}

__global__ void k_final(const float* __restrict__ pooled, const float* __restrict__ Z,
                        const float* __restrict__ Wc1, const float* __restrict__ bc1,
                        const float* __restrict__ Wc2, const float* __restrict__ bc2,
                        float* __restrict__ out){
    __shared__ float sp[64], sz[32];
    int t = threadIdx.x;
    float scale = 1.0f / ((*Z) * (float)N_NODES);
    sp[t] = pooled[t] * scale;
    __syncthreads();
    if (t < 32){
        float s = bc1[t];
        #pragma unroll 8
        for (int j = 0; j < 64; j++) s += sp[j] * Wc1[j * 32 + t];
        sz[t] = fmaxf(s, 0.f);
    }
    __syncthreads();
    if (t == 0){
        float s = bc2[0];
        #pragma unroll
        for (int i = 0; i < 32; i++) s += sz[i] * Wc2[i];
        out[0] = 1.0f / (1.0f + expf(-s));
    }
}

extern "C" void kernel_launch(void* const* d_in, const int* in_sizes, int n_in,
                              void* d_out, int out_size, void* d_ws, size_t ws_size,
                              hipStream_t stream) {
    const float* x   = (const float*)d_in[0];
    const int*   ei  = (const int*)d_in[1];
    const int*   src = ei;
    const int*   dst = ei + E_EDGES;
    const float* W1l = (const float*)d_in[2];
    const float* W1r = (const float*)d_in[3];
    const float* b1  = (const float*)d_in[4];
    const float* W2l = (const float*)d_in[5];
    const float* W2r = (const float*)d_in[6];
    const float* b2  = (const float*)d_in[7];
    const float* Wa  = (const float*)d_in[8];
    const float* ba  = (const float*)d_in[9];
    const float* ctx = (const float*)d_in[10];
    const float* Wc1 = (const float*)d_in[11];
    const float* bc1 = (const float*)d_in[12];
    const float* Wc2 = (const float*)d_in[13];
    const float* bc2 = (const float*)d_in[14];

    char* p = (char*)d_ws;
    int* cnt    = (int*)p;                 p += (size_t)N_NODES * 4;
    int* rowptr = (int*)p;                 p += (size_t)N_NODES * 4;
    int* rowcur = (int*)p;                 p += (size_t)N_NODES * 4;
    int* bsum   = (int*)p;                 p += 128 * 4;
    int* bscan  = (int*)p;                 p += 128 * 4;
    int* ssrc   = (int*)p;                 p += (size_t)E_EDGES * 4;
    uint32* xb  = (uint32*)p;              p += (size_t)N_NODES * 32 * 4;
    uint32* xq  = (uint32*)p;              p += (size_t)N_NODES * 16 * 4;
    uint32* mean1b = (uint32*)p;           p += (size_t)N_NODES * 32 * 4;
    ushort* vh  = (ushort*)p;              p += (size_t)N_NODES * 64 * 2;
    uint32* vq  = (uint32*)p;              p += (size_t)N_NODES * 16 * 4;
    float* r2f  = (float*)p;               p += (size_t)N_NODES * 64 * 4;
    float* h2   = (float*)p;               p += (size_t)N_NODES * 64 * 4;
    float* wlogit = (float*)p;             p += (size_t)N_NODES * 4;
    ushort* wt1g = (ushort*)p;             p += 128 * 128 * 2;
    ushort* wt2g = (ushort*)p;             p += 128 * 128 * 2;
    float* pooled = (float*)p;             p += 64 * 4;
    float* Zp     = (float*)p;             p += 4;
    unsigned* maxu = (unsigned*)p;

    hipMemsetAsync(cnt, 0, (size_t)N_NODES * 4, stream);
    k_init<<<1, 128, 0, stream>>>(pooled, Zp, maxu);

    k_xcast<<<(N_NODES * 16 + 255) / 256, 256, 0, stream>>>(x, xb, xq);
    k_prep<<<2, 256, 0, stream>>>(W1l, W1r, W2l, W2r, wt1g, wt2g);
    k_hist<<<(E_EDGES + 255) / 256, 256, 0, stream>>>(dst, cnt);
    k_scan1<<<NB_SCAN, 256, 0, stream>>>(cnt, bsum);
    k_scan2<<<1, 128, 0, stream>>>(bsum, bscan);
    k_scan3<<<NB_SCAN, 256, 0, stream>>>(cnt, bscan, rowptr, rowcur);
    k_scatter<<<1024, 256, 0, stream>>>(src, dst, rowcur, ssrc);

    k_gather1<<<N_NODES / 4, 256, 0, stream>>>(xq, ssrc, rowptr, cnt, mean1b);
    k_dense1<<<N_NODES / 16, 256, 0, stream>>>(mean1b, xb, wt1g, wt2g, b1, b2, vh, r2f);
    k_vcast<<<(N_NODES * 16 + 255) / 256, 256, 0, stream>>>((const uint32*)vh, vq);
    k_gather2<<<N_NODES / 4, 256, 0, stream>>>(x, vq, ssrc, rowptr, cnt,
                                               r2f, Wa, ba, ctx, h2, wlogit);

    k_max<<<512, 256, 0, stream>>>(wlogit, maxu);
    k_pool<<<1024, 256, 0, stream>>>(h2, wlogit, maxu, pooled, Zp);
    k_final<<<1, 64, 0, stream>>>(pooled, Zp, Wc1, bc1, Wc2, bc2, (float*)d_out);
}

// Round 7
// 504.874 us; speedup vs baseline: 1.9836x; 1.0131x over previous
//
#include <hip/hip_runtime.h>
#include <math.h>

#define N_NODES 100000
#define E_EDGES 1600000
#define D_IN 64
#define HID1 128
#define HID2 64
#define ATT 32
#define CHUNK 1024
#define NB_SCAN ((N_NODES + CHUNK - 1) / CHUNK)   // 98
#define AT_STRIDE 136   // 128 + 8 bf16 pad: keeps ds_read_b128 16B-aligned, 2-way banks
#define NRANGE 8
#define RNODES (N_NODES / NRANGE)  // 12500

typedef unsigned int uint32;
typedef unsigned short ushort;
typedef __attribute__((ext_vector_type(8))) short short8;
typedef __attribute__((ext_vector_type(4))) float float4v;

__device__ inline unsigned f2o(float f){ unsigned u = __float_as_uint(f); return (u >> 31) ? ~u : (u | 0x80000000u); }
__device__ inline float o2f(unsigned u){ return (u >> 31) ? __uint_as_float(u & 0x7fffffffu) : __uint_as_float(~u); }

__device__ inline uint32 bf16rn(float f){ uint32 u = __float_as_uint(f); return (u + 0x7fffu + ((u >> 16) & 1u)) >> 16; }
__device__ inline uint32 packbf2(float a, float b){ return bf16rn(a) | (bf16rn(b) << 16); }
__device__ inline float2 unpackbf2(uint32 v){ float2 r; r.x = __uint_as_float(v << 16); r.y = __uint_as_float(v & 0xffff0000u); return r; }

// ---- fp8 e4m3fn helpers (HW cvt on gfx950; exact SW fallback) ----
#if __has_builtin(__builtin_amdgcn_cvt_f32_fp8) && __has_builtin(__builtin_amdgcn_cvt_pk_fp8_f32)
#define HW_FP8 1
#endif

__device__ inline uint32 fp8_enc_sw(float f){
    float a = fabsf(f);
    uint32 s = (__float_as_uint(f) >> 24) & 0x80u;
    if (!(a >= 0.001953125f)) return s;
    if (a > 448.f) return s | 0x7Eu;
    if (a < 0.015625f){
        uint32 c = (uint32)rintf(a * 512.f);
        return s | c;
    }
    int e; float m = frexpf(a, &e);
    int E = e - 1;
    float mant = 2.f * m;
    uint32 mc = (uint32)rintf((mant - 1.f) * 8.f);
    uint32 Ec = (uint32)(E + 7);
    if (mc == 8u){ mc = 0u; Ec += 1u; }
    if (Ec >= 16u || (Ec == 15u && mc > 6u)) return s | 0x7Eu;
    return s | (Ec << 3) | mc;
}

__device__ inline float fp8_dec_sw(uint32 c){
    uint32 s = (c & 0x80u) << 24;
    uint32 E = (c >> 3) & 0xFu, m = c & 7u;
    float v;
    if (E == 0) v = (float)m * 0.001953125f;
    else v = __uint_as_float(((E + 120u) << 23) | (m << 20));
    return __uint_as_float(__float_as_uint(v) | s);
}

__device__ inline uint32 enc4(float a, float b, float c, float d){
#ifdef HW_FP8
    int r = __builtin_amdgcn_cvt_pk_fp8_f32(a, b, 0, false);
    r = __builtin_amdgcn_cvt_pk_fp8_f32(c, d, r, true);
    return (uint32)r;
#else
    return fp8_enc_sw(a) | (fp8_enc_sw(b) << 8) | (fp8_enc_sw(c) << 16) | (fp8_enc_sw(d) << 24);
#endif
}

__device__ inline void dec4acc(uint32 w, float& a0, float& a1, float& a2, float& a3){
#ifdef HW_FP8
    a0 += __builtin_amdgcn_cvt_f32_fp8((int)w, 0);
    a1 += __builtin_amdgcn_cvt_f32_fp8((int)w, 1);
    a2 += __builtin_amdgcn_cvt_f32_fp8((int)w, 2);
    a3 += __builtin_amdgcn_cvt_f32_fp8((int)w, 3);
#else
    a0 += fp8_dec_sw(w & 0xffu);
    a1 += fp8_dec_sw((w >> 8) & 0xffu);
    a2 += fp8_dec_sw((w >> 16) & 0xffu);
    a3 += fp8_dec_sw(w >> 24);
#endif
}

__global__ void k_init(float* pooled, float* Z, unsigned* maxu){
    int t = threadIdx.x;
    if (t < 64) pooled[t] = 0.f;
    if (t == 64) *Z = 0.f;
    if (t == 65) *maxu = f2o(-INFINITY);
}

__global__ void k_xcast(const float* __restrict__ x, uint32* __restrict__ xb, uint32* __restrict__ xq){
    int i = blockIdx.x * 256 + threadIdx.x;
    if (i < N_NODES * 16){
        float4 v = ((const float4*)x)[i];
        xb[2 * i]     = packbf2(v.x, v.y);
        xb[2 * i + 1] = packbf2(v.z, v.w);
        xq[i] = enc4(v.x, v.y, v.z, v.w);
    }
}

__global__ void k_vcast(const uint32* __restrict__ vh, uint32* __restrict__ vq){
    int i = blockIdx.x * 256 + threadIdx.x;
    if (i < N_NODES * 16){
        uint2 w = ((const uint2*)vh)[i];
        float2 v0 = unpackbf2(w.x), v1 = unpackbf2(w.y);
        vq[i] = enc4(v0.x, v0.y, v1.x, v1.y);
    }
}

__global__ void k_prep(const float* __restrict__ W1l, const float* __restrict__ W1r,
                       const float* __restrict__ W2l, const float* __restrict__ W2r,
                       ushort* __restrict__ wt1g, ushort* __restrict__ wt2g){
    __shared__ ushort st[128 * 130];
    int t = threadIdx.x;
    int n = t & 127, kh = t >> 7;
    if (blockIdx.x == 0){
        for (int k0 = 0; k0 < 128; k0 += 2){
            int k = k0 + kh;
            float v = (k < 64) ? W1l[k * 128 + n] : W1r[(k - 64) * 128 + n];
            st[k * 130 + n] = (ushort)bf16rn(v);
        }
    } else {
        for (int k0 = 0; k0 < 128; k0 += 2){
            int k = k0 + kh;
            float v = (n < 64) ? W2l[k * 64 + n] : W2r[k * 64 + (n - 64)];
            st[k * 130 + n] = (ushort)bf16rn(v);
        }
    }
    __syncthreads();
    ushort* dstp = (blockIdx.x == 0) ? wt1g : wt2g;
    int kk = t & 127, nh = t >> 7;
    for (int n0 = 0; n0 < 128; n0 += 2){
        int nn = n0 + nh;
        dstp[nn * 128 + kk] = st[kk * 130 + nn];
    }
}

__global__ void k_hist(const int* __restrict__ dst, int* __restrict__ cnt){
    int i = blockIdx.x * blockDim.x + threadIdx.x;
    if (i < E_EDGES) atomicAdd(&cnt[dst[i]], 1);
}

__global__ void k_scan1(const int* __restrict__ cnt, int* __restrict__ bsum){
    int base = blockIdx.x * CHUNK + threadIdx.x * 4;
    int s = 0;
    #pragma unroll
    for (int k = 0; k < 4; k++){ int i = base + k; if (i < N_NODES) s += cnt[i]; }
    #pragma unroll
    for (int off = 32; off >= 1; off >>= 1) s += __shfl_down(s, off, 64);
    __shared__ int sm[4];
    if ((threadIdx.x & 63) == 0) sm[threadIdx.x >> 6] = s;
    __syncthreads();
    if (threadIdx.x == 0) bsum[blockIdx.x] = sm[0] + sm[1] + sm[2] + sm[3];
}

__global__ void k_scan2(const int* __restrict__ bsum, int* __restrict__ bscan){
    __shared__ int sb[NB_SCAN];
    int t = threadIdx.x;
    if (t < NB_SCAN) sb[t] = bsum[t];
    __syncthreads();
    if (t == 0){ int run = 0; for (int i = 0; i < NB_SCAN; i++){ int v = sb[i]; sb[i] = run; run += v; } }
    __syncthreads();
    if (t < NB_SCAN) bscan[t] = sb[t];
}

__global__ void k_scan3(const int* __restrict__ cnt, const int* __restrict__ bscan,
                        int* __restrict__ rowptr, int* __restrict__ rowcur){
    __shared__ int ts[256];
    int t = threadIdx.x;
    int base = blockIdx.x * CHUNK + t * 4;
    int v[4]; int s = 0;
    #pragma unroll
    for (int k = 0; k < 4; k++){ int i = base + k; v[k] = (i < N_NODES) ? cnt[i] : 0; s += v[k]; }
    ts[t] = s;
    __syncthreads();
    int total = s;
    for (int off = 1; off < 256; off <<= 1){
        int a = 0;
        if (t >= off) a = ts[t - off];
        __syncthreads();
        ts[t] += a;
        __syncthreads();
    }
    int excl = ts[t] - total + bscan[blockIdx.x];
    #pragma unroll
    for (int k = 0; k < 4; k++){
        int i = base + k;
        if (i < N_NODES){ rowptr[i] = excl; rowcur[i] = excl; excl += v[k]; }
    }
}

__global__ void k_scatter(const int* __restrict__ src, const int* __restrict__ dst,
                          int* __restrict__ rowcur, int* __restrict__ ssrc){
    int range = blockIdx.x & (NRANGE - 1);
    int blk   = blockIdx.x >> 3;
    int lo = range * RNODES, hi = lo + RNODES;
    int stride = (gridDim.x >> 3) * blockDim.x;
    for (int i = blk * blockDim.x + threadIdx.x; i < E_EDGES; i += stride){
        int d = dst[i];
        if (d >= lo && d < hi){
            int pos = atomicAdd(&rowcur[d], 1);
            ssrc[pos] = src[i];
        }
    }
}

// 4-node interleaved fp8 gather: wave handles nodes n0..n0+3 with independent
// chains -> 4+ gather loads in flight. Lane: q=lane>>4 picks edge-in-quad,
// p=lane&15 holds dims 4p..4p+3. After call all lanes hold full sums in acc.
__device__ inline void gather4_fp8(const uint32* __restrict__ tab,
                                   const int* __restrict__ ssrc,
                                   const int* __restrict__ rowptr,
                                   const int* __restrict__ cnt,
                                   int n0, int lane,
                                   float acc[4][4], int cc[4]){
    int q = lane >> 4, p = lane & 15;
    int nn = n0 + (lane & 3);
    int bgl = rowptr[nn], ccl = cnt[nn];
    int bg[4];
    #pragma unroll
    for (int j = 0; j < 4; j++){ bg[j] = __shfl(bgl, j, 64); cc[j] = __shfl(ccl, j, 64); }
    #pragma unroll
    for (int j = 0; j < 4; j++){ acc[j][0] = acc[j][1] = acc[j][2] = acc[j][3] = 0.f; }
    int cmax = max(max(cc[0], cc[1]), max(cc[2], cc[3]));
    for (int base = 0; base < cmax; base += 64){
        int se[4];
        #pragma unroll
        for (int j = 0; j < 4; j++){
            int rem = cc[j] - base;
            se[j] = (lane < rem) ? ssrc[bg[j] + base + lane] : 0;
        }
        int vis = cmax - base; if (vis > 64) vis = 64;
        int iters = (vis + 3) >> 2;
        for (int it = 0; it < iters; it++){
            int idx = it * 4 + q;
            #pragma unroll
            for (int j = 0; j < 4; j++){
                int s = __shfl(se[j], idx, 64);
                int rem = cc[j] - base; if (rem > 64) rem = 64;
                if (idx < rem){
                    uint32 w = tab[(size_t)s * 16 + p];
                    dec4acc(w, acc[j][0], acc[j][1], acc[j][2], acc[j][3]);
                }
            }
        }
    }
    #pragma unroll
    for (int j = 0; j < 4; j++){
        acc[j][0] += __shfl_xor(acc[j][0], 16, 64); acc[j][1] += __shfl_xor(acc[j][1], 16, 64);
        acc[j][2] += __shfl_xor(acc[j][2], 16, 64); acc[j][3] += __shfl_xor(acc[j][3], 16, 64);
        acc[j][0] += __shfl_xor(acc[j][0], 32, 64); acc[j][1] += __shfl_xor(acc[j][1], 32, 64);
        acc[j][2] += __shfl_xor(acc[j][2], 32, 64); acc[j][3] += __shfl_xor(acc[j][3], 32, 64);
    }
}

// 16 nodes/block (4 waves x 4 nodes)
__global__ void k_gather1(const uint32* __restrict__ xq, const int* __restrict__ ssrc,
                          const int* __restrict__ rowptr, const int* __restrict__ cnt,
                          uint32* __restrict__ mean1b){
    int wave = threadIdx.x >> 6, lane = threadIdx.x & 63;
    int n0 = blockIdx.x * 16 + wave * 4;
    float acc[4][4]; int cc[4];
    gather4_fp8(xq, ssrc, rowptr, cnt, n0, lane, acc, cc);
    int p = lane & 15;
    if (lane < 16){
        #pragma unroll
        for (int j = 0; j < 4; j++){
            float inv = 1.f / fmaxf((float)cc[j], 1.f);
            uint2 o;
            o.x = packbf2(acc[j][0] * inv, acc[j][1] * inv);
            o.y = packbf2(acc[j][2] * inv, acc[j][3] * inv);
            *(uint2*)&mean1b[(size_t)(n0 + j) * 32 + 2 * p] = o;
        }
    }
}

// MFMA dense: h1 = relu([mean1|x]@wt1 + b1); [v|r2] = h1@wt2 (+b2 on r2 half)
__global__ __launch_bounds__(256) void k_dense1(
    const uint32* __restrict__ mean1b, const uint32* __restrict__ xb,
    const ushort* __restrict__ wt1g, const ushort* __restrict__ wt2g,
    const float* __restrict__ b1, const float* __restrict__ b2,
    ushort* __restrict__ vh, float* __restrict__ r2f){
    __shared__ ushort at[16 * AT_STRIDE];
    __shared__ ushort at2[16 * AT_STRIDE];
    int t = threadIdx.x;
    int nb0 = blockIdx.x * 16;
    {
        int m = t >> 4;
        int q = (t & 15) * 4;
        size_t node = nb0 + m;
        uint4 val;
        if (q < 32) val = *(const uint4*)&mean1b[node * 32 + q];
        else        val = *(const uint4*)&xb[node * 32 + (q - 32)];
        *(uint4*)((uint32*)at + (m * (AT_STRIDE / 2) + q)) = val;
    }
    __syncthreads();
    int lane = t & 63, wave = t >> 6;
    int cidx = lane & 15, quad = lane >> 4;
    int nbA = wave * 32, nbB = wave * 32 + 16;
    float4v acc0 = {0.f,0.f,0.f,0.f}, acc1 = {0.f,0.f,0.f,0.f};
    #pragma unroll
    for (int s = 0; s < 4; s++){
        short8 a  = *(short8*)(at + (cidx * AT_STRIDE + s * 32 + quad * 8));
        short8 bA = *(const short8*)(wt1g + ((nbA + cidx) * 128 + s * 32 + quad * 8));
        short8 bB = *(const short8*)(wt1g + ((nbB + cidx) * 128 + s * 32 + quad * 8));
        acc0 = __builtin_amdgcn_mfma_f32_16x16x32_bf16(a, bA, acc0, 0, 0, 0);
        acc1 = __builtin_amdgcn_mfma_f32_16x16x32_bf16(a, bB, acc1, 0, 0, 0);
    }
    float b1A = b1[nbA + cidx], b1B = b1[nbB + cidx];
    #pragma unroll
    for (int i = 0; i < 4; i++){
        int row = quad * 4 + i;
        at2[row * AT_STRIDE + nbA + cidx] = (ushort)bf16rn(fmaxf(acc0[i] + b1A, 0.f));
        at2[row * AT_STRIDE + nbB + cidx] = (ushort)bf16rn(fmaxf(acc1[i] + b1B, 0.f));
    }
    __syncthreads();
    float4v c0 = {0.f,0.f,0.f,0.f}, c1 = {0.f,0.f,0.f,0.f};
    #pragma unroll
    for (int s = 0; s < 4; s++){
        short8 a  = *(short8*)(at2 + (cidx * AT_STRIDE + s * 32 + quad * 8));
        short8 bA = *(const short8*)(wt2g + ((nbA + cidx) * 128 + s * 32 + quad * 8));
        short8 bB = *(const short8*)(wt2g + ((nbB + cidx) * 128 + s * 32 + quad * 8));
        c0 = __builtin_amdgcn_mfma_f32_16x16x32_bf16(a, bA, c0, 0, 0, 0);
        c1 = __builtin_amdgcn_mfma_f32_16x16x32_bf16(a, bB, c1, 0, 0, 0);
    }
    #pragma unroll
    for (int i = 0; i < 4; i++){
        int row = quad * 4 + i;
        size_t node = nb0 + row;
        int colA = nbA + cidx;
        if (colA < 64) vh[node * 64 + colA] = (ushort)bf16rn(c0[i]);
        else           r2f[node * 64 + (colA - 64)] = c0[i] + b2[colA - 64];
        int colB = nbB + cidx;
        if (colB < 64) vh[node * 64 + colB] = (ushort)bf16rn(c1[i]);
        else           r2f[node * 64 + (colB - 64)] = c1[i] + b2[colB - 64];
    }
}

// 16 nodes/block: interleaved gather + LDS h2 + block attention phase
__global__ void k_gather2(const float* __restrict__ x, const uint32* __restrict__ vq,
                          const int* __restrict__ ssrc, const int* __restrict__ rowptr,
                          const int* __restrict__ cnt, const float* __restrict__ r2f,
                          const float* __restrict__ Wa, const float* __restrict__ ba,
                          const float* __restrict__ ctx,
                          float* __restrict__ h2, float* __restrict__ wlogit){
    __shared__ float sh2[16][64];
    int wave = threadIdx.x >> 6, lane = threadIdx.x & 63;
    int bn0 = blockIdx.x * 16;
    int n0 = bn0 + wave * 4;
    float acc[4][4]; int cc[4];
    gather4_fp8(vq, ssrc, rowptr, cnt, n0, lane, acc, cc);
    int p = lane & 15;
    if (lane < 16){
        #pragma unroll
        for (int j = 0; j < 4; j++){
            size_t nj = n0 + j;
            float inv = 1.f / fmaxf((float)cc[j], 1.f);
            float4 rr = *(const float4*)&r2f[nj * 64 + 4 * p];
            float4 hv;
            hv.x = fmaxf(acc[j][0] * inv + rr.x, 0.f);
            hv.y = fmaxf(acc[j][1] * inv + rr.y, 0.f);
            hv.z = fmaxf(acc[j][2] * inv + rr.z, 0.f);
            hv.w = fmaxf(acc[j][3] * inv + rr.w, 0.f);
            *(float4*)&h2[nj * 64 + 4 * p] = hv;
            *(float4*)&sh2[wave * 4 + j][4 * p] = hv;
        }
    }
    __syncthreads();
    // attention: 16 threads per node, 2 att-cols each
    int t = threadIdx.x;
    int node = t >> 4;
    int c0 = (t & 15) * 2;
    float s0 = ba[c0], s1 = ba[c0 + 1];
    #pragma unroll 8
    for (int j = 0; j < 64; j++){
        float hv = sh2[node][j];
        s0 += hv * Wa[j * ATT + c0];
        s1 += hv * Wa[j * ATT + c0 + 1];
    }
    float pa = tanhf(s0) * ctx[c0] + tanhf(s1) * ctx[c0 + 1];
    #pragma unroll
    for (int off = 8; off >= 1; off >>= 1) pa += __shfl_down(pa, off, 16);
    if ((t & 15) == 0){
        int n = bn0 + node;
        wlogit[n] = pa + x[(size_t)n * 64 + 63] * 0.4f;
    }
}

__global__ void k_max(const float* __restrict__ wlogit, unsigned* __restrict__ maxu){
    float m = -INFINITY;
    for (size_t i = (size_t)blockIdx.x * blockDim.x + threadIdx.x; i < N_NODES; i += (size_t)gridDim.x * blockDim.x)
        m = fmaxf(m, wlogit[i]);
    #pragma unroll
    for (int off = 32; off >= 1; off >>= 1) m = fmaxf(m, __shfl_down(m, off, 64));
    __shared__ float sm[4];
    if ((threadIdx.x & 63) == 0) sm[threadIdx.x >> 6] = m;
    __syncthreads();
    if (threadIdx.x == 0){
        float mm = fmaxf(fmaxf(sm[0], sm[1]), fmaxf(sm[2], sm[3]));
        atomicMax(maxu, f2o(mm));
    }
}

__global__ void k_pool(const float* __restrict__ h2, const float* __restrict__ wlogit,
                       const unsigned* __restrict__ maxu, float* __restrict__ pooled, float* __restrict__ Z){
    float mv = o2f(*maxu);
    int lane = threadIdx.x & 63;
    int row  = threadIdx.x >> 6;
    float pacc = 0.f, zacc = 0.f;
    for (size_t n = (size_t)blockIdx.x * 4 + row; n < N_NODES; n += (size_t)gridDim.x * 4){
        float e = expf(wlogit[n] - mv);
        pacc += h2[n * 64 + lane] * e;
        zacc += e;
    }
    __shared__ float sp[4][64];
    sp[row][lane] = pacc;
    __syncthreads();
    if (threadIdx.x < 64){
        float s = sp[0][threadIdx.x] + sp[1][threadIdx.x] + sp[2][threadIdx.x] + sp[3][threadIdx.x];
        atomicAdd(&pooled[threadIdx.x], s);
    }
    if (lane == 0) atomicAdd(Z, zacc);
}

__global__ void k_final(const float* __restrict__ pooled, const float* __restrict__ Z,
                        const float* __restrict__ Wc1, const float* __restrict__ bc1,
                        const float* __restrict__ Wc2, const float* __restrict__ bc2,
                        float* __restrict__ out){
    __shared__ float sp[64], sz[32];
    int t = threadIdx.x;
    float scale = 1.0f / ((*Z) * (float)N_NODES);
    sp[t] = pooled[t] * scale;
    __syncthreads();
    if (t < 32){
        float s = bc1[t];
        #pragma unroll 8
        for (int j = 0; j < 64; j++) s += sp[j] * Wc1[j * 32 + t];
        sz[t] = fmaxf(s, 0.f);
    }
    __syncthreads();
    if (t == 0){
        float s = bc2[0];
        #pragma unroll
        for (int i = 0; i < 32; i++) s += sz[i] * Wc2[i];
        out[0] = 1.0f / (1.0f + expf(-s));
    }
}

extern "C" void kernel_launch(void* const* d_in, const int* in_sizes, int n_in,
                              void* d_out, int out_size, void* d_ws, size_t ws_size,
                              hipStream_t stream) {
    const float* x   = (const float*)d_in[0];
    const int*   ei  = (const int*)d_in[1];
    const int*   src = ei;
    const int*   dst = ei + E_EDGES;
    const float* W1l = (const float*)d_in[2];
    const float* W1r = (const float*)d_in[3];
    const float* b1  = (const float*)d_in[4];
    const float* W2l = (const float*)d_in[5];
    const float* W2r = (const float*)d_in[6];
    const float* b2  = (const float*)d_in[7];
    const float* Wa  = (const float*)d_in[8];
    const float* ba  = (const float*)d_in[9];
    const float* ctx = (const float*)d_in[10];
    const float* Wc1 = (const float*)d_in[11];
    const float* bc1 = (const float*)d_in[12];
    const float* Wc2 = (const float*)d_in[13];
    const float* bc2 = (const float*)d_in[14];

    char* p = (char*)d_ws;
    int* cnt    = (int*)p;                 p += (size_t)N_NODES * 4;
    int* rowptr = (int*)p;                 p += (size_t)N_NODES * 4;
    int* rowcur = (int*)p;                 p += (size_t)N_NODES * 4;
    int* bsum   = (int*)p;                 p += 128 * 4;
    int* bscan  = (int*)p;                 p += 128 * 4;
    int* ssrc   = (int*)p;                 p += (size_t)E_EDGES * 4;
    uint32* xb  = (uint32*)p;              p += (size_t)N_NODES * 32 * 4;
    uint32* xq  = (uint32*)p;              p += (size_t)N_NODES * 16 * 4;
    uint32* mean1b = (uint32*)p;           p += (size_t)N_NODES * 32 * 4;
    ushort* vh  = (ushort*)p;              p += (size_t)N_NODES * 64 * 2;
    uint32* vq  = (uint32*)p;              p += (size_t)N_NODES * 16 * 4;
    float* r2f  = (float*)p;               p += (size_t)N_NODES * 64 * 4;
    float* h2   = (float*)p;               p += (size_t)N_NODES * 64 * 4;
    float* wlogit = (float*)p;             p += (size_t)N_NODES * 4;
    ushort* wt1g = (ushort*)p;             p += 128 * 128 * 2;
    ushort* wt2g = (ushort*)p;             p += 128 * 128 * 2;
    float* pooled = (float*)p;             p += 64 * 4;
    float* Zp     = (float*)p;             p += 4;
    unsigned* maxu = (unsigned*)p;

    hipMemsetAsync(cnt, 0, (size_t)N_NODES * 4, stream);
    k_init<<<1, 128, 0, stream>>>(pooled, Zp, maxu);

    k_xcast<<<(N_NODES * 16 + 255) / 256, 256, 0, stream>>>(x, xb, xq);
    k_prep<<<2, 256, 0, stream>>>(W1l, W1r, W2l, W2r, wt1g, wt2g);
    k_hist<<<(E_EDGES + 255) / 256, 256, 0, stream>>>(dst, cnt);
    k_scan1<<<NB_SCAN, 256, 0, stream>>>(cnt, bsum);
    k_scan2<<<1, 128, 0, stream>>>(bsum, bscan);
    k_scan3<<<NB_SCAN, 256, 0, stream>>>(cnt, bscan, rowptr, rowcur);
    k_scatter<<<1024, 256, 0, stream>>>(src, dst, rowcur, ssrc);

    k_gather1<<<N_NODES / 16, 256, 0, stream>>>(xq, ssrc, rowptr, cnt, mean1b);
    k_dense1<<<N_NODES / 16, 256, 0, stream>>>(mean1b, xb, wt1g, wt2g, b1, b2, vh, r2f);
    k_vcast<<<(N_NODES * 16 + 255) / 256, 256, 0, stream>>>((const uint32*)vh, vq);
    k_gather2<<<N_NODES / 16, 256, 0, stream>>>(x, vq, ssrc, rowptr, cnt,
                                                r2f, Wa, ba, ctx, h2, wlogit);

    k_max<<<512, 256, 0, stream>>>(wlogit, maxu);
    k_pool<<<1024, 256, 0, stream>>>(h2, wlogit, maxu, pooled, Zp);
    k_final<<<1, 64, 0, stream>>>(pooled, Zp, Wc1, bc1, Wc2, bc2, (float*)d_out);
}

// Round 9
// 425.786 us; speedup vs baseline: 2.3521x; 1.1857x over previous
//
#include <hip/hip_runtime.h>
#include <math.h>

#define N_NODES 100000
#define E_EDGES 1600000
#define D_IN 64
#define HID1 128
#define HID2 64
#define ATT 32
#define CHUNK 1024
#define NB_SCAN ((N_NODES + CHUNK - 1) / CHUNK)   // 98
#define AT_STRIDE 136   // 128 + 8 bf16 pad: 16B-aligned ds_read_b128, 2-way banks (free)
#define NRANGE 8
#define RNODES (N_NODES / NRANGE)  // 12500
#define NPART 64

typedef unsigned int uint32;
typedef unsigned short ushort;
typedef __attribute__((ext_vector_type(8))) short short8;
typedef __attribute__((ext_vector_type(4))) float float4v;   // native vector (NTL-compatible)

#define NTL(p) __builtin_nontemporal_load(&(p))

__device__ inline uint32 bf16rn(float f){ uint32 u = __float_as_uint(f); return (u + 0x7fffu + ((u >> 16) & 1u)) >> 16; }
__device__ inline uint32 packbf2(float a, float b){ return bf16rn(a) | (bf16rn(b) << 16); }
__device__ inline float2 unpackbf2(uint32 v){ float2 r; r.x = __uint_as_float(v << 16); r.y = __uint_as_float(v & 0xffff0000u); return r; }

// ---- fp8 e4m3fn helpers (HW cvt on gfx950; exact SW fallback) ----
#if __has_builtin(__builtin_amdgcn_cvt_f32_fp8) && __has_builtin(__builtin_amdgcn_cvt_pk_fp8_f32)
#define HW_FP8 1
#endif

__device__ inline uint32 fp8_enc_sw(float f){
    float a = fabsf(f);
    uint32 s = (__float_as_uint(f) >> 24) & 0x80u;
    if (!(a >= 0.001953125f)) return s;
    if (a > 448.f) return s | 0x7Eu;
    if (a < 0.015625f){
        uint32 c = (uint32)rintf(a * 512.f);
        return s | c;
    }
    int e; float m = frexpf(a, &e);
    int E = e - 1;
    float mant = 2.f * m;
    uint32 mc = (uint32)rintf((mant - 1.f) * 8.f);
    uint32 Ec = (uint32)(E + 7);
    if (mc == 8u){ mc = 0u; Ec += 1u; }
    if (Ec >= 16u || (Ec == 15u && mc > 6u)) return s | 0x7Eu;
    return s | (Ec << 3) | mc;
}

__device__ inline float fp8_dec_sw(uint32 c){
    uint32 s = (c & 0x80u) << 24;
    uint32 E = (c >> 3) & 0xFu, m = c & 7u;
    float v;
    if (E == 0) v = (float)m * 0.001953125f;
    else v = __uint_as_float(((E + 120u) << 23) | (m << 20));
    return __uint_as_float(__float_as_uint(v) | s);
}

__device__ inline uint32 enc4(float a, float b, float c, float d){
#ifdef HW_FP8
    int r = __builtin_amdgcn_cvt_pk_fp8_f32(a, b, 0, false);
    r = __builtin_amdgcn_cvt_pk_fp8_f32(c, d, r, true);
    return (uint32)r;
#else
    return fp8_enc_sw(a) | (fp8_enc_sw(b) << 8) | (fp8_enc_sw(c) << 16) | (fp8_enc_sw(d) << 24);
#endif
}

__device__ inline void dec4acc(uint32 w, float& a0, float& a1, float& a2, float& a3){
#ifdef HW_FP8
    a0 += __builtin_amdgcn_cvt_f32_fp8((int)w, 0);
    a1 += __builtin_amdgcn_cvt_f32_fp8((int)w, 1);
    a2 += __builtin_amdgcn_cvt_f32_fp8((int)w, 2);
    a3 += __builtin_amdgcn_cvt_f32_fp8((int)w, 3);
#else
    a0 += fp8_dec_sw(w & 0xffu);
    a1 += fp8_dec_sw((w >> 8) & 0xffu);
    a2 += fp8_dec_sw((w >> 16) & 0xffu);
    a3 += fp8_dec_sw(w >> 24);
#endif
}

__global__ void k_xcast(const float* __restrict__ x, uint32* __restrict__ xb, uint32* __restrict__ xq){
    int i = blockIdx.x * 256 + threadIdx.x;
    if (i < N_NODES * 16){
        float4v v = NTL(((const float4v*)x)[i]);
        xb[2 * i]     = packbf2(v.x, v.y);
        xb[2 * i + 1] = packbf2(v.z, v.w);
        xq[i] = enc4(v.x, v.y, v.z, v.w);
    }
}

__global__ void k_prep(const float* __restrict__ W1l, const float* __restrict__ W1r,
                       const float* __restrict__ W2l, const float* __restrict__ W2r,
                       ushort* __restrict__ wt1g, ushort* __restrict__ wt2g){
    __shared__ ushort st[128 * 130];
    int t = threadIdx.x;
    int n = t & 127, kh = t >> 7;
    if (blockIdx.x == 0){
        for (int k0 = 0; k0 < 128; k0 += 2){
            int k = k0 + kh;
            float v = (k < 64) ? W1l[k * 128 + n] : W1r[(k - 64) * 128 + n];
            st[k * 130 + n] = (ushort)bf16rn(v);
        }
    } else {
        for (int k0 = 0; k0 < 128; k0 += 2){
            int k = k0 + kh;
            float v = (n < 64) ? W2l[k * 64 + n] : W2r[k * 64 + (n - 64)];
            st[k * 130 + n] = (ushort)bf16rn(v);
        }
    }
    __syncthreads();
    ushort* dstp = (blockIdx.x == 0) ? wt1g : wt2g;
    int kk = t & 127, nh = t >> 7;
    for (int n0 = 0; n0 < 128; n0 += 2){
        int nn = n0 + nh;
        dstp[nn * 128 + kk] = st[kk * 130 + nn];
    }
}

__global__ void k_hist(const int* __restrict__ dst, int* __restrict__ cnt){
    int i = blockIdx.x * blockDim.x + threadIdx.x;
    if (i < E_EDGES) atomicAdd(&cnt[NTL(dst[i])], 1);
}

__global__ void k_scan1(const int* __restrict__ cnt, int* __restrict__ bsum){
    int base = blockIdx.x * CHUNK + threadIdx.x * 4;
    int s = 0;
    #pragma unroll
    for (int k = 0; k < 4; k++){ int i = base + k; if (i < N_NODES) s += cnt[i]; }
    #pragma unroll
    for (int off = 32; off >= 1; off >>= 1) s += __shfl_down(s, off, 64);
    __shared__ int sm[4];
    if ((threadIdx.x & 63) == 0) sm[threadIdx.x >> 6] = s;
    __syncthreads();
    if (threadIdx.x == 0) bsum[blockIdx.x] = sm[0] + sm[1] + sm[2] + sm[3];
}

__global__ void k_scan2(const int* __restrict__ bsum, int* __restrict__ bscan){
    __shared__ int sb[NB_SCAN];
    int t = threadIdx.x;
    if (t < NB_SCAN) sb[t] = bsum[t];
    __syncthreads();
    if (t == 0){ int run = 0; for (int i = 0; i < NB_SCAN; i++){ int v = sb[i]; sb[i] = run; run += v; } }
    __syncthreads();
    if (t < NB_SCAN) bscan[t] = sb[t];
}

__global__ void k_scan3(const int* __restrict__ cnt, const int* __restrict__ bscan,
                        int* __restrict__ rowptr, int* __restrict__ rowcur){
    __shared__ int ts[256];
    int t = threadIdx.x;
    int base = blockIdx.x * CHUNK + t * 4;
    int v[4]; int s = 0;
    #pragma unroll
    for (int k = 0; k < 4; k++){ int i = base + k; v[k] = (i < N_NODES) ? cnt[i] : 0; s += v[k]; }
    ts[t] = s;
    __syncthreads();
    int total = s;
    for (int off = 1; off < 256; off <<= 1){
        int a = 0;
        if (t >= off) a = ts[t - off];
        __syncthreads();
        ts[t] += a;
        __syncthreads();
    }
    int excl = ts[t] - total + bscan[blockIdx.x];
    #pragma unroll
    for (int k = 0; k < 4; k++){
        int i = base + k;
        if (i < N_NODES){ rowptr[i] = excl; rowcur[i] = excl; excl += v[k]; }
    }
}

__global__ void k_scatter(const int* __restrict__ src, const int* __restrict__ dst,
                          int* __restrict__ rowcur, int* __restrict__ ssrc){
    int range = blockIdx.x & (NRANGE - 1);
    int blk   = blockIdx.x >> 3;
    int lo = range * RNODES, hi = lo + RNODES;
    int stride = (gridDim.x >> 3) * blockDim.x;
    for (int i = blk * blockDim.x + threadIdx.x; i < E_EDGES; i += stride){
        int d = NTL(dst[i]);
        if (d >= lo && d < hi){
            int pos = atomicAdd(&rowcur[d], 1);
            ssrc[pos] = NTL(src[i]);
        }
    }
}

// 4-node interleaved fp8 gather (q=lane>>4 edge-in-quad, p=lane&15 holds dims 4p..4p+3)
__device__ inline void gather4_fp8(const uint32* __restrict__ tab,
                                   const int* __restrict__ ssrc,
                                   const int* __restrict__ rowptr,
                                   const int* __restrict__ cnt,
                                   int n0, int lane,
                                   float acc[4][4], int cc[4]){
    int q = lane >> 4, p = lane & 15;
    int nn = n0 + (lane & 3);
    int bgl = rowptr[nn], ccl = cnt[nn];
    int bg[4];
    #pragma unroll
    for (int j = 0; j < 4; j++){ bg[j] = __shfl(bgl, j, 64); cc[j] = __shfl(ccl, j, 64); }
    #pragma unroll
    for (int j = 0; j < 4; j++){ acc[j][0] = acc[j][1] = acc[j][2] = acc[j][3] = 0.f; }
    int cmax = max(max(cc[0], cc[1]), max(cc[2], cc[3]));
    for (int base = 0; base < cmax; base += 64){
        int se[4];
        #pragma unroll
        for (int j = 0; j < 4; j++){
            int rem = cc[j] - base;
            se[j] = (lane < rem) ? NTL(ssrc[bg[j] + base + lane]) : 0;
        }
        int vis = cmax - base; if (vis > 64) vis = 64;
        int iters = (vis + 3) >> 2;
        for (int it = 0; it < iters; it++){
            int idx = it * 4 + q;
            #pragma unroll
            for (int j = 0; j < 4; j++){
                int s = __shfl(se[j], idx, 64);
                int rem = cc[j] - base; if (rem > 64) rem = 64;
                if (idx < rem){
                    uint32 w = tab[(size_t)s * 16 + p];
                    dec4acc(w, acc[j][0], acc[j][1], acc[j][2], acc[j][3]);
                }
            }
        }
    }
    #pragma unroll
    for (int j = 0; j < 4; j++){
        acc[j][0] += __shfl_xor(acc[j][0], 16, 64); acc[j][1] += __shfl_xor(acc[j][1], 16, 64);
        acc[j][2] += __shfl_xor(acc[j][2], 16, 64); acc[j][3] += __shfl_xor(acc[j][3], 16, 64);
        acc[j][0] += __shfl_xor(acc[j][0], 32, 64); acc[j][1] += __shfl_xor(acc[j][1], 32, 64);
        acc[j][2] += __shfl_xor(acc[j][2], 32, 64); acc[j][3] += __shfl_xor(acc[j][3], 32, 64);
    }
}

// FUSED layer1: gather-mean(xq) -> LDS A-tile -> MFMA h1 -> MFMA [v|r2]
// 16 nodes/block (4 waves x 4 nodes gather; 16x128 MFMA tile)
__global__ __launch_bounds__(256) void k_layer1(
    const uint32* __restrict__ xq, const uint32* __restrict__ xb,
    const int* __restrict__ ssrc, const int* __restrict__ rowptr, const int* __restrict__ cnt,
    const ushort* __restrict__ wt1g, const ushort* __restrict__ wt2g,
    const float* __restrict__ b1, const float* __restrict__ b2,
    uint32* __restrict__ vq, float* __restrict__ r2f){
    __shared__ ushort at[16 * AT_STRIDE];
    __shared__ ushort at2[16 * AT_STRIDE];
    __shared__ float vstage[16][65];
    int t = threadIdx.x, wave = t >> 6, lane = t & 63;
    int nb0 = blockIdx.x * 16;
    int n0 = nb0 + wave * 4;

    // x-half of A-tile (issue load early)
    int m0 = t >> 4, q2 = (t & 15) * 2;
    uint2 xval = *(const uint2*)&xb[(size_t)(nb0 + m0) * 32 + q2];

    float acc[4][4]; int cc[4];
    gather4_fp8(xq, ssrc, rowptr, cnt, n0, lane, acc, cc);
    int p = lane & 15;
    if (lane < 16){
        #pragma unroll
        for (int j = 0; j < 4; j++){
            float inv = 1.f / fmaxf((float)cc[j], 1.f);
            uint2 o;
            o.x = packbf2(acc[j][0] * inv, acc[j][1] * inv);
            o.y = packbf2(acc[j][2] * inv, acc[j][3] * inv);
            *(uint2*)&at[(wave * 4 + j) * AT_STRIDE + 4 * p] = o;
        }
    }
    *(uint2*)&at[m0 * AT_STRIDE + 64 + 2 * q2] = xval;
    __syncthreads();

    int cidx = lane & 15, quad = lane >> 4;
    int nbA = wave * 32, nbB = wave * 32 + 16;
    float4v acc0 = {0.f,0.f,0.f,0.f}, acc1 = {0.f,0.f,0.f,0.f};
    #pragma unroll
    for (int s = 0; s < 4; s++){
        short8 a  = *(short8*)(at + (cidx * AT_STRIDE + s * 32 + quad * 8));
        short8 bA = *(const short8*)(wt1g + ((nbA + cidx) * 128 + s * 32 + quad * 8));
        short8 bB = *(const short8*)(wt1g + ((nbB + cidx) * 128 + s * 32 + quad * 8));
        acc0 = __builtin_amdgcn_mfma_f32_16x16x32_bf16(a, bA, acc0, 0, 0, 0);
        acc1 = __builtin_amdgcn_mfma_f32_16x16x32_bf16(a, bB, acc1, 0, 0, 0);
    }
    float b1A = b1[nbA + cidx], b1B = b1[nbB + cidx];
    #pragma unroll
    for (int i = 0; i < 4; i++){
        int row = quad * 4 + i;
        at2[row * AT_STRIDE + nbA + cidx] = (ushort)bf16rn(fmaxf(acc0[i] + b1A, 0.f));
        at2[row * AT_STRIDE + nbB + cidx] = (ushort)bf16rn(fmaxf(acc1[i] + b1B, 0.f));
    }
    __syncthreads();
    float4v c0 = {0.f,0.f,0.f,0.f}, c1 = {0.f,0.f,0.f,0.f};
    #pragma unroll
    for (int s = 0; s < 4; s++){
        short8 a  = *(short8*)(at2 + (cidx * AT_STRIDE + s * 32 + quad * 8));
        short8 bA = *(const short8*)(wt2g + ((nbA + cidx) * 128 + s * 32 + quad * 8));
        short8 bB = *(const short8*)(wt2g + ((nbB + cidx) * 128 + s * 32 + quad * 8));
        c0 = __builtin_amdgcn_mfma_f32_16x16x32_bf16(a, bA, c0, 0, 0, 0);
        c1 = __builtin_amdgcn_mfma_f32_16x16x32_bf16(a, bB, c1, 0, 0, 0);
    }
    // waves 0,1 produce v (cols 0..63) -> vstage; waves 2,3 produce r2 (cols 64..127) -> global
    if (nbA < 64){
        #pragma unroll
        for (int i = 0; i < 4; i++){
            int row = quad * 4 + i;
            vstage[row][nbA + cidx] = c0[i];
            vstage[row][nbB + cidx] = c1[i];
        }
    } else {
        float b2A = b2[nbA + cidx - 64], b2B = b2[nbB + cidx - 64];
        #pragma unroll
        for (int i = 0; i < 4; i++){
            int row = quad * 4 + i;
            size_t node = nb0 + row;
            r2f[node * 64 + (nbA + cidx - 64)] = c0[i] + b2A;
            r2f[node * 64 + (nbB + cidx - 64)] = c1[i] + b2B;
        }
    }
    __syncthreads();
    {
        int m = t >> 4, u = t & 15;
        float f0 = vstage[m][4 * u], f1 = vstage[m][4 * u + 1];
        float f2 = vstage[m][4 * u + 2], f3 = vstage[m][4 * u + 3];
        vq[(size_t)(nb0 + m) * 16 + u] = enc4(f0, f1, f2, f3);
    }
}

// FUSED layer2: gather-mean(vq) + r2 -> h2 (LDS only) -> attention logit ->
// unnormalized-softmax pool partials (bounded logits: |tanh.ctx|<=sum|ctx|~26, exp safe in fp32)
__global__ __launch_bounds__(256) void k_gather2f(
    const float* __restrict__ x, const uint32* __restrict__ vq,
    const int* __restrict__ ssrc, const int* __restrict__ rowptr, const int* __restrict__ cnt,
    const float* __restrict__ r2f,
    const float* __restrict__ Wa, const float* __restrict__ ba, const float* __restrict__ ctx,
    float* __restrict__ pooledP, float* __restrict__ Zpart){
    __shared__ float sh2[16][68];   // stride 68: 16B-aligned float4, 2-way banks (free)
    __shared__ float sew[16];
    __shared__ float sp[4][64];
    int t = threadIdx.x, wave = t >> 6, lane = t & 63;
    int bn0 = blockIdx.x * 16;
    int n0 = bn0 + wave * 4;
    float acc[4][4]; int cc[4];
    gather4_fp8(vq, ssrc, rowptr, cnt, n0, lane, acc, cc);
    int p = lane & 15;
    if (lane < 16){
        #pragma unroll
        for (int j = 0; j < 4; j++){
            size_t nj = n0 + j;
            float inv = 1.f / fmaxf((float)cc[j], 1.f);
            float4v rr = NTL(*(const float4v*)&r2f[nj * 64 + 4 * p]);
            float4v hv;
            hv.x = fmaxf(acc[j][0] * inv + rr.x, 0.f);
            hv.y = fmaxf(acc[j][1] * inv + rr.y, 0.f);
            hv.z = fmaxf(acc[j][2] * inv + rr.z, 0.f);
            hv.w = fmaxf(acc[j][3] * inv + rr.w, 0.f);
            *(float4v*)&sh2[wave * 4 + j][4 * p] = hv;
        }
    }
    __syncthreads();
    // attention: 16 threads per node, 2 att-cols each
    int node = t >> 4;
    int c0 = (t & 15) * 2;
    float s0 = ba[c0], s1 = ba[c0 + 1];
    #pragma unroll 8
    for (int j = 0; j < 64; j++){
        float hv = sh2[node][j];
        s0 += hv * Wa[j * ATT + c0];
        s1 += hv * Wa[j * ATT + c0 + 1];
    }
    float pa = tanhf(s0) * ctx[c0] + tanhf(s1) * ctx[c0 + 1];
    #pragma unroll
    for (int off = 8; off >= 1; off >>= 1) pa += __shfl_down(pa, off, 16);
    if ((t & 15) == 0){
        int n = bn0 + node;
        float w = pa + NTL(x[(size_t)n * 64 + 63]) * 0.4f;
        sew[node] = expf(w);
    }
    __syncthreads();
    // pool partials: thread t -> col j, quarter q
    int j = t & 63, q = t >> 6;
    float p4 = 0.f;
    #pragma unroll
    for (int m = 0; m < 4; m++) p4 += sh2[q * 4 + m][j] * sew[q * 4 + m];
    sp[q][j] = p4;
    __syncthreads();
    if (t < 64){
        float s = sp[0][t] + sp[1][t] + sp[2][t] + sp[3][t];
        atomicAdd(&pooledP[(blockIdx.x & (NPART - 1)) * 64 + t], s);
    }
    if (t == 64){
        float z = 0.f;
        #pragma unroll
        for (int m = 0; m < 16; m++) z += sew[m];
        atomicAdd(&Zpart[blockIdx.x & (NPART - 1)], z);
    }
}

__global__ void k_final(const float* __restrict__ pooledP, const float* __restrict__ Zpart,
                        const float* __restrict__ Wc1, const float* __restrict__ bc1,
                        const float* __restrict__ Wc2, const float* __restrict__ bc2,
                        float* __restrict__ out){
    __shared__ float sp[64], sz[32];
    __shared__ float Zs;
    int t = threadIdx.x;  // 64 threads
    float s = 0.f;
    for (int q = 0; q < NPART; q++) s += pooledP[q * 64 + t];
    if (t == 0){
        float z = 0.f;
        for (int q = 0; q < NPART; q++) z += Zpart[q];
        Zs = z;
    }
    __syncthreads();
    float scale = 1.0f / (Zs * (float)N_NODES);
    sp[t] = s * scale;
    __syncthreads();
    if (t < 32){
        float a = bc1[t];
        #pragma unroll 8
        for (int j = 0; j < 64; j++) a += sp[j] * Wc1[j * 32 + t];
        sz[t] = fmaxf(a, 0.f);
    }
    __syncthreads();
    if (t == 0){
        float a = bc2[0];
        #pragma unroll
        for (int i = 0; i < 32; i++) a += sz[i] * Wc2[i];
        out[0] = 1.0f / (1.0f + expf(-a));
    }
}

extern "C" void kernel_launch(void* const* d_in, const int* in_sizes, int n_in,
                              void* d_out, int out_size, void* d_ws, size_t ws_size,
                              hipStream_t stream) {
    const float* x   = (const float*)d_in[0];
    const int*   ei  = (const int*)d_in[1];
    const int*   src = ei;
    const int*   dst = ei + E_EDGES;
    const float* W1l = (const float*)d_in[2];
    const float* W1r = (const float*)d_in[3];
    const float* b1  = (const float*)d_in[4];
    const float* W2l = (const float*)d_in[5];
    const float* W2r = (const float*)d_in[6];
    const float* b2  = (const float*)d_in[7];
    const float* Wa  = (const float*)d_in[8];
    const float* ba  = (const float*)d_in[9];
    const float* ctx = (const float*)d_in[10];
    const float* Wc1 = (const float*)d_in[11];
    const float* bc1 = (const float*)d_in[12];
    const float* Wc2 = (const float*)d_in[13];
    const float* bc2 = (const float*)d_in[14];

    char* p = (char*)d_ws;
    int* cnt    = (int*)p;                 p += (size_t)N_NODES * 4;
    int* rowptr = (int*)p;                 p += (size_t)N_NODES * 4;
    int* rowcur = (int*)p;                 p += (size_t)N_NODES * 4;
    int* bsum   = (int*)p;                 p += 128 * 4;
    int* bscan  = (int*)p;                 p += 128 * 4;
    int* ssrc   = (int*)p;                 p += (size_t)E_EDGES * 4;
    uint32* xb  = (uint32*)p;              p += (size_t)N_NODES * 32 * 4;
    uint32* xq  = (uint32*)p;              p += (size_t)N_NODES * 16 * 4;
    uint32* vq  = (uint32*)p;              p += (size_t)N_NODES * 16 * 4;
    float* r2f  = (float*)p;               p += (size_t)N_NODES * 64 * 4;
    ushort* wt1g = (ushort*)p;             p += 128 * 128 * 2;
    ushort* wt2g = (ushort*)p;             p += 128 * 128 * 2;
    float* pooledP = (float*)p;            p += NPART * 64 * 4;
    float* Zpart   = (float*)p;            p += NPART * 4;

    hipMemsetAsync(cnt, 0, (size_t)N_NODES * 4, stream);
    hipMemsetAsync(pooledP, 0, (NPART * 64 + NPART) * 4, stream);

    k_xcast<<<(N_NODES * 16 + 255) / 256, 256, 0, stream>>>(x, xb, xq);
    k_prep<<<2, 256, 0, stream>>>(W1l, W1r, W2l, W2r, wt1g, wt2g);
    k_hist<<<(E_EDGES + 255) / 256, 256, 0, stream>>>(dst, cnt);
    k_scan1<<<NB_SCAN, 256, 0, stream>>>(cnt, bsum);
    k_scan2<<<1, 128, 0, stream>>>(bsum, bscan);
    k_scan3<<<NB_SCAN, 256, 0, stream>>>(cnt, bscan, rowptr, rowcur);
    k_scatter<<<1024, 256, 0, stream>>>(src, dst, rowcur, ssrc);

    k_layer1<<<N_NODES / 16, 256, 0, stream>>>(xq, xb, ssrc, rowptr, cnt,
                                               wt1g, wt2g, b1, b2, vq, r2f);
    k_gather2f<<<N_NODES / 16, 256, 0, stream>>>(x, vq, ssrc, rowptr, cnt, r2f,
                                                 Wa, ba, ctx, pooledP, Zpart);
    k_final<<<1, 64, 0, stream>>>(pooledP, Zpart, Wc1, bc1, Wc2, bc2, (float*)d_out);
}

// Round 10
// 393.042 us; speedup vs baseline: 2.5480x; 1.0833x over previous
//
#include <hip/hip_runtime.h>
#include <math.h>

#define N_NODES 100000
#define E_EDGES 1600000
#define D_IN 64
#define HID1 128
#define HID2 64
#define ATT 32
#define CHUNK 1024
#define NB_SCAN ((N_NODES + CHUNK - 1) / CHUNK)   // 98
#define AT_STRIDE 136   // 128 + 8 bf16 pad: 16B-aligned ds_read_b128, 2-way banks (free)
#define NRANGE 8
#define RNODES (N_NODES / NRANGE)  // 12500
#define NPART 64

typedef unsigned int uint32;
typedef unsigned short ushort;
typedef __attribute__((ext_vector_type(8))) short short8;
typedef __attribute__((ext_vector_type(4))) float float4v;

#define NTL(p) __builtin_nontemporal_load(&(p))

__device__ inline uint32 bf16rn(float f){ uint32 u = __float_as_uint(f); return (u + 0x7fffu + ((u >> 16) & 1u)) >> 16; }
__device__ inline uint32 packbf2(float a, float b){ return bf16rn(a) | (bf16rn(b) << 16); }
__device__ inline float2 unpackbf2(uint32 v){ float2 r; r.x = __uint_as_float(v << 16); r.y = __uint_as_float(v & 0xffff0000u); return r; }

// ---- fp8 e4m3fn helpers (HW cvt on gfx950; exact SW fallback) ----
#if __has_builtin(__builtin_amdgcn_cvt_f32_fp8) && __has_builtin(__builtin_amdgcn_cvt_pk_fp8_f32)
#define HW_FP8 1
#endif

__device__ inline uint32 fp8_enc_sw(float f){
    float a = fabsf(f);
    uint32 s = (__float_as_uint(f) >> 24) & 0x80u;
    if (!(a >= 0.001953125f)) return s;
    if (a > 448.f) return s | 0x7Eu;
    if (a < 0.015625f){
        uint32 c = (uint32)rintf(a * 512.f);
        return s | c;
    }
    int e; float m = frexpf(a, &e);
    int E = e - 1;
    float mant = 2.f * m;
    uint32 mc = (uint32)rintf((mant - 1.f) * 8.f);
    uint32 Ec = (uint32)(E + 7);
    if (mc == 8u){ mc = 0u; Ec += 1u; }
    if (Ec >= 16u || (Ec == 15u && mc > 6u)) return s | 0x7Eu;
    return s | (Ec << 3) | mc;
}

__device__ inline float fp8_dec_sw(uint32 c){
    uint32 s = (c & 0x80u) << 24;
    uint32 E = (c >> 3) & 0xFu, m = c & 7u;
    float v;
    if (E == 0) v = (float)m * 0.001953125f;
    else v = __uint_as_float(((E + 120u) << 23) | (m << 20));
    return __uint_as_float(__float_as_uint(v) | s);
}

__device__ inline uint32 enc4(float a, float b, float c, float d){
#ifdef HW_FP8
    int r = __builtin_amdgcn_cvt_pk_fp8_f32(a, b, 0, false);
    r = __builtin_amdgcn_cvt_pk_fp8_f32(c, d, r, true);
    return (uint32)r;
#else
    return fp8_enc_sw(a) | (fp8_enc_sw(b) << 8) | (fp8_enc_sw(c) << 16) | (fp8_enc_sw(d) << 24);
#endif
}

__device__ inline void dec4acc(uint32 w, float& a0, float& a1, float& a2, float& a3){
#ifdef HW_FP8
    a0 += __builtin_amdgcn_cvt_f32_fp8((int)w, 0);
    a1 += __builtin_amdgcn_cvt_f32_fp8((int)w, 1);
    a2 += __builtin_amdgcn_cvt_f32_fp8((int)w, 2);
    a3 += __builtin_amdgcn_cvt_f32_fp8((int)w, 3);
#else
    a0 += fp8_dec_sw(w & 0xffu);
    a1 += fp8_dec_sw((w >> 8) & 0xffu);
    a2 += fp8_dec_sw((w >> 16) & 0xffu);
    a3 += fp8_dec_sw(w >> 24);
#endif
}

__global__ void k_xcast(const float* __restrict__ x, uint32* __restrict__ xb, uint32* __restrict__ xq){
    int i = blockIdx.x * 256 + threadIdx.x;
    if (i < N_NODES * 16){
        float4v v = NTL(((const float4v*)x)[i]);
        xb[2 * i]     = packbf2(v.x, v.y);
        xb[2 * i + 1] = packbf2(v.z, v.w);
        xq[i] = enc4(v.x, v.y, v.z, v.w);
    }
}

__global__ void k_prep(const float* __restrict__ W1l, const float* __restrict__ W1r,
                       const float* __restrict__ W2l, const float* __restrict__ W2r,
                       ushort* __restrict__ wt1g, ushort* __restrict__ wt2g){
    __shared__ ushort st[128 * 130];
    int t = threadIdx.x;
    int n = t & 127, kh = t >> 7;
    if (blockIdx.x == 0){
        for (int k0 = 0; k0 < 128; k0 += 2){
            int k = k0 + kh;
            float v = (k < 64) ? W1l[k * 128 + n] : W1r[(k - 64) * 128 + n];
            st[k * 130 + n] = (ushort)bf16rn(v);
        }
    } else {
        for (int k0 = 0; k0 < 128; k0 += 2){
            int k = k0 + kh;
            float v = (n < 64) ? W2l[k * 64 + n] : W2r[k * 64 + (n - 64)];
            st[k * 130 + n] = (ushort)bf16rn(v);
        }
    }
    __syncthreads();
    ushort* dstp = (blockIdx.x == 0) ? wt1g : wt2g;
    int kk = t & 127, nh = t >> 7;
    for (int n0 = 0; n0 < 128; n0 += 2){
        int nn = n0 + nh;
        dstp[nn * 128 + kk] = st[kk * 130 + nn];
    }
}

__global__ void k_hist(const int* __restrict__ dst, int* __restrict__ cnt){
    int i = blockIdx.x * blockDim.x + threadIdx.x;
    if (i < E_EDGES) atomicAdd(&cnt[NTL(dst[i])], 1);
}

__global__ void k_scan1(const int* __restrict__ cnt, int* __restrict__ bsum){
    int base = blockIdx.x * CHUNK + threadIdx.x * 4;
    int s = 0;
    #pragma unroll
    for (int k = 0; k < 4; k++){ int i = base + k; if (i < N_NODES) s += cnt[i]; }
    #pragma unroll
    for (int off = 32; off >= 1; off >>= 1) s += __shfl_down(s, off, 64);
    __shared__ int sm[4];
    if ((threadIdx.x & 63) == 0) sm[threadIdx.x >> 6] = s;
    __syncthreads();
    if (threadIdx.x == 0) bsum[blockIdx.x] = sm[0] + sm[1] + sm[2] + sm[3];
}

__global__ void k_scan2(const int* __restrict__ bsum, int* __restrict__ bscan){
    __shared__ int sb[NB_SCAN];
    int t = threadIdx.x;
    if (t < NB_SCAN) sb[t] = bsum[t];
    __syncthreads();
    if (t == 0){ int run = 0; for (int i = 0; i < NB_SCAN; i++){ int v = sb[i]; sb[i] = run; run += v; } }
    __syncthreads();
    if (t < NB_SCAN) bscan[t] = sb[t];
}

__global__ void k_scan3(const int* __restrict__ cnt, const int* __restrict__ bscan,
                        int* __restrict__ rowptr, int* __restrict__ rowcur){
    __shared__ int ts[256];
    int t = threadIdx.x;
    int base = blockIdx.x * CHUNK + t * 4;
    int v[4]; int s = 0;
    #pragma unroll
    for (int k = 0; k < 4; k++){ int i = base + k; v[k] = (i < N_NODES) ? cnt[i] : 0; s += v[k]; }
    ts[t] = s;
    __syncthreads();
    int total = s;
    for (int off = 1; off < 256; off <<= 1){
        int a = 0;
        if (t >= off) a = ts[t - off];
        __syncthreads();
        ts[t] += a;
        __syncthreads();
    }
    int excl = ts[t] - total + bscan[blockIdx.x];
    #pragma unroll
    for (int k = 0; k < 4; k++){
        int i = base + k;
        if (i < N_NODES){ rowptr[i] = excl; rowcur[i] = excl; excl += v[k]; }
    }
}

__global__ void k_scatter(const int* __restrict__ src, const int* __restrict__ dst,
                          int* __restrict__ rowcur, int* __restrict__ ssrc){
    int range = blockIdx.x & (NRANGE - 1);
    int blk   = blockIdx.x >> 3;
    int lo = range * RNODES, hi = lo + RNODES;
    int stride = (gridDim.x >> 3) * blockDim.x;
    for (int i = blk * blockDim.x + threadIdx.x; i < E_EDGES; i += stride){
        int d = NTL(dst[i]);
        if (d >= lo && d < hi){
            int pos = atomicAdd(&rowcur[d], 1);
            ssrc[pos] = NTL(src[i]);
        }
    }
}

// 8-node interleaved fp8 gather: wave handles nodes n0..n0+7, 8 independent
// chains -> 8 batched loads per inner iteration (loads split from decodes).
// q=lane>>4 edge-in-quad, p=lane&15 holds dims 4p..4p+3.
__device__ inline void gather8_fp8(const uint32* __restrict__ tab,
                                   const int* __restrict__ ssrc,
                                   const int* __restrict__ rowptr,
                                   const int* __restrict__ cnt,
                                   int n0, int lane,
                                   float acc[8][4], int cc[8]){
    int q = lane >> 4, p = lane & 15;
    int nn = n0 + (lane & 7);
    int bgl = rowptr[nn], ccl = cnt[nn];
    int bg[8];
    #pragma unroll
    for (int j = 0; j < 8; j++){ bg[j] = __shfl(bgl, j, 64); cc[j] = __shfl(ccl, j, 64); }
    #pragma unroll
    for (int j = 0; j < 8; j++){ acc[j][0] = acc[j][1] = acc[j][2] = acc[j][3] = 0.f; }
    int cmax = 0;
    #pragma unroll
    for (int j = 0; j < 8; j++) cmax = max(cmax, cc[j]);
    for (int base = 0; base < cmax; base += 64){
        int se[8];
        #pragma unroll
        for (int j = 0; j < 8; j++){
            int rem = cc[j] - base;
            se[j] = (lane < rem) ? NTL(ssrc[bg[j] + base + lane]) : 0;
        }
        int vis = cmax - base; if (vis > 64) vis = 64;
        int iters = (vis + 3) >> 2;
        for (int it = 0; it < iters; it++){
            int idx = it * 4 + q;
            uint32 w[8];
            #pragma unroll
            for (int j = 0; j < 8; j++){
                int s = __shfl(se[j], idx, 64);
                int rem = cc[j] - base; if (rem > 64) rem = 64;
                w[j] = 0;
                if (idx < rem) w[j] = tab[(size_t)s * 16 + p];
            }
            #pragma unroll
            for (int j = 0; j < 8; j++)
                dec4acc(w[j], acc[j][0], acc[j][1], acc[j][2], acc[j][3]);
        }
    }
    #pragma unroll
    for (int j = 0; j < 8; j++){
        acc[j][0] += __shfl_xor(acc[j][0], 16, 64); acc[j][1] += __shfl_xor(acc[j][1], 16, 64);
        acc[j][2] += __shfl_xor(acc[j][2], 16, 64); acc[j][3] += __shfl_xor(acc[j][3], 16, 64);
        acc[j][0] += __shfl_xor(acc[j][0], 32, 64); acc[j][1] += __shfl_xor(acc[j][1], 32, 64);
        acc[j][2] += __shfl_xor(acc[j][2], 32, 64); acc[j][3] += __shfl_xor(acc[j][3], 32, 64);
    }
}

// FUSED layer1: gather-mean(xq) -> LDS A-tile (32x128) -> MFMA h1 -> MFMA [v|r2]
// 32 nodes/block (4 waves x 8 nodes gather; 2 M-tiles x 2 col-halves MFMA)
__global__ __launch_bounds__(256) void k_layer1(
    const uint32* __restrict__ xq, const uint32* __restrict__ xb,
    const int* __restrict__ ssrc, const int* __restrict__ rowptr, const int* __restrict__ cnt,
    const ushort* __restrict__ wt1g, const ushort* __restrict__ wt2g,
    const float* __restrict__ b1, const float* __restrict__ b2,
    uint32* __restrict__ vq, float* __restrict__ r2f){
    __shared__ ushort at[32 * AT_STRIDE];
    __shared__ ushort at2[32 * AT_STRIDE];
    __shared__ float vstage[32][65];
    int t = threadIdx.x, wave = t >> 6, lane = t & 63;
    int nb0 = blockIdx.x * 32;
    int n0 = nb0 + wave * 8;

    // x-half of A-tile: node m0 = t>>3, chunk = t&7 (uint4 = 8 bf16)
    int m0 = t >> 3, ch = t & 7;
    uint4 xval = *(const uint4*)&xb[(size_t)(nb0 + m0) * 32 + ch * 4];

    float acc[8][4]; int cc[8];
    gather8_fp8(xq, ssrc, rowptr, cnt, n0, lane, acc, cc);
    int p = lane & 15;
    if (lane < 16){
        #pragma unroll
        for (int j = 0; j < 8; j++){
            float inv = 1.f / fmaxf((float)cc[j], 1.f);
            uint2 o;
            o.x = packbf2(acc[j][0] * inv, acc[j][1] * inv);
            o.y = packbf2(acc[j][2] * inv, acc[j][3] * inv);
            *(uint2*)&at[(wave * 8 + j) * AT_STRIDE + 4 * p] = o;
        }
    }
    *(uint4*)((uint32*)(at + m0 * AT_STRIDE + 64) + ch * 4) = xval;
    __syncthreads();

    int cidx = lane & 15, quad = lane >> 4;
    int mt = wave >> 1;                 // M-tile 0..1 (rows mt*16..mt*16+15)
    int nbase = (wave & 1) * 64;        // col half
    float4v c[4];
    #pragma unroll
    for (int nt = 0; nt < 4; nt++) c[nt] = (float4v){0.f,0.f,0.f,0.f};
    #pragma unroll
    for (int kt = 0; kt < 4; kt++){
        short8 a = *(short8*)(at + ((mt * 16 + cidx) * AT_STRIDE + kt * 32 + quad * 8));
        #pragma unroll
        for (int nt = 0; nt < 4; nt++){
            short8 b = *(const short8*)(wt1g + ((nbase + nt * 16 + cidx) * 128 + kt * 32 + quad * 8));
            c[nt] = __builtin_amdgcn_mfma_f32_16x16x32_bf16(a, b, c[nt], 0, 0, 0);
        }
    }
    #pragma unroll
    for (int nt = 0; nt < 4; nt++){
        float bb = b1[nbase + nt * 16 + cidx];
        #pragma unroll
        for (int i = 0; i < 4; i++){
            int row = quad * 4 + i;
            at2[(mt * 16 + row) * AT_STRIDE + nbase + nt * 16 + cidx] =
                (ushort)bf16rn(fmaxf(c[nt][i] + bb, 0.f));
        }
    }
    __syncthreads();
    #pragma unroll
    for (int nt = 0; nt < 4; nt++) c[nt] = (float4v){0.f,0.f,0.f,0.f};
    #pragma unroll
    for (int kt = 0; kt < 4; kt++){
        short8 a = *(short8*)(at2 + ((mt * 16 + cidx) * AT_STRIDE + kt * 32 + quad * 8));
        #pragma unroll
        for (int nt = 0; nt < 4; nt++){
            short8 b = *(const short8*)(wt2g + ((nbase + nt * 16 + cidx) * 128 + kt * 32 + quad * 8));
            c[nt] = __builtin_amdgcn_mfma_f32_16x16x32_bf16(a, b, c[nt], 0, 0, 0);
        }
    }
    if (nbase == 0){
        // v columns 0..63 -> vstage
        #pragma unroll
        for (int nt = 0; nt < 4; nt++){
            #pragma unroll
            for (int i = 0; i < 4; i++){
                int row = quad * 4 + i;
                vstage[mt * 16 + row][nt * 16 + cidx] = c[nt][i];
            }
        }
    } else {
        // r2 columns 0..63 -> global (+bias)
        #pragma unroll
        for (int nt = 0; nt < 4; nt++){
            float bb = b2[nt * 16 + cidx];
            #pragma unroll
            for (int i = 0; i < 4; i++){
                int row = quad * 4 + i;
                size_t node = nb0 + mt * 16 + row;
                r2f[node * 64 + nt * 16 + cidx] = c[nt][i] + bb;
            }
        }
    }
    __syncthreads();
    {
        int m = t >> 3, u = t & 7;   // node, 8-dim chunk
        float f0 = vstage[m][8 * u],     f1 = vstage[m][8 * u + 1];
        float f2 = vstage[m][8 * u + 2], f3 = vstage[m][8 * u + 3];
        float f4 = vstage[m][8 * u + 4], f5 = vstage[m][8 * u + 5];
        float f6 = vstage[m][8 * u + 6], f7 = vstage[m][8 * u + 7];
        vq[(size_t)(nb0 + m) * 16 + 2 * u]     = enc4(f0, f1, f2, f3);
        vq[(size_t)(nb0 + m) * 16 + 2 * u + 1] = enc4(f4, f5, f6, f7);
    }
}

// FUSED layer2: gather-mean(vq) + r2 -> h2 (LDS) -> attention -> softmax-pool partials
// 32 nodes/block
__global__ __launch_bounds__(256) void k_gather2f(
    const float* __restrict__ x, const uint32* __restrict__ vq,
    const int* __restrict__ ssrc, const int* __restrict__ rowptr, const int* __restrict__ cnt,
    const float* __restrict__ r2f,
    const float* __restrict__ Wa, const float* __restrict__ ba, const float* __restrict__ ctx,
    float* __restrict__ pooledP, float* __restrict__ Zpart){
    __shared__ float sh2[32][68];
    __shared__ float sew[32];
    __shared__ float sp[4][64];
    int t = threadIdx.x, wave = t >> 6, lane = t & 63;
    int bn0 = blockIdx.x * 32;
    int n0 = bn0 + wave * 8;
    float acc[8][4]; int cc[8];
    gather8_fp8(vq, ssrc, rowptr, cnt, n0, lane, acc, cc);
    int p = lane & 15;
    if (lane < 16){
        #pragma unroll
        for (int j = 0; j < 8; j++){
            size_t nj = n0 + j;
            float inv = 1.f / fmaxf((float)cc[j], 1.f);
            float4v rr = NTL(*(const float4v*)&r2f[nj * 64 + 4 * p]);
            float4v hv;
            hv.x = fmaxf(acc[j][0] * inv + rr.x, 0.f);
            hv.y = fmaxf(acc[j][1] * inv + rr.y, 0.f);
            hv.z = fmaxf(acc[j][2] * inv + rr.z, 0.f);
            hv.w = fmaxf(acc[j][3] * inv + rr.w, 0.f);
            *(float4v*)&sh2[wave * 8 + j][4 * p] = hv;
        }
    }
    __syncthreads();
    // attention: 8 threads per node, 4 att-cols each
    int node = t >> 3;
    int c0 = (t & 7) * 4;
    float s0 = ba[c0], s1 = ba[c0 + 1], s2 = ba[c0 + 2], s3 = ba[c0 + 3];
    #pragma unroll 8
    for (int j = 0; j < 64; j++){
        float hv = sh2[node][j];
        s0 += hv * Wa[j * ATT + c0];
        s1 += hv * Wa[j * ATT + c0 + 1];
        s2 += hv * Wa[j * ATT + c0 + 2];
        s3 += hv * Wa[j * ATT + c0 + 3];
    }
    float pa = tanhf(s0) * ctx[c0] + tanhf(s1) * ctx[c0 + 1]
             + tanhf(s2) * ctx[c0 + 2] + tanhf(s3) * ctx[c0 + 3];
    #pragma unroll
    for (int off = 4; off >= 1; off >>= 1) pa += __shfl_down(pa, off, 8);
    if ((t & 7) == 0){
        int n = bn0 + node;
        float w = pa + NTL(x[(size_t)n * 64 + 63]) * 0.4f;
        sew[node] = expf(w);
    }
    __syncthreads();
    // pool partials: thread t -> col j, group q of 8 nodes
    int j = t & 63, q = t >> 6;
    float p4 = 0.f;
    #pragma unroll
    for (int m = 0; m < 8; m++) p4 += sh2[q * 8 + m][j] * sew[q * 8 + m];
    sp[q][j] = p4;
    __syncthreads();
    if (t < 64){
        float s = sp[0][t] + sp[1][t] + sp[2][t] + sp[3][t];
        atomicAdd(&pooledP[(blockIdx.x & (NPART - 1)) * 64 + t], s);
    }
    if (t == 64){
        float z = 0.f;
        #pragma unroll
        for (int m = 0; m < 32; m++) z += sew[m];
        atomicAdd(&Zpart[blockIdx.x & (NPART - 1)], z);
    }
}

__global__ void k_final(const float* __restrict__ pooledP, const float* __restrict__ Zpart,
                        const float* __restrict__ Wc1, const float* __restrict__ bc1,
                        const float* __restrict__ Wc2, const float* __restrict__ bc2,
                        float* __restrict__ out){
    __shared__ float sp[64], sz[32];
    __shared__ float Zs;
    int t = threadIdx.x;  // 64 threads
    float s = 0.f;
    for (int q = 0; q < NPART; q++) s += pooledP[q * 64 + t];
    if (t == 0){
        float z = 0.f;
        for (int q = 0; q < NPART; q++) z += Zpart[q];
        Zs = z;
    }
    __syncthreads();
    float scale = 1.0f / (Zs * (float)N_NODES);
    sp[t] = s * scale;
    __syncthreads();
    if (t < 32){
        float a = bc1[t];
        #pragma unroll 8
        for (int j = 0; j < 64; j++) a += sp[j] * Wc1[j * 32 + t];
        sz[t] = fmaxf(a, 0.f);
    }
    __syncthreads();
    if (t == 0){
        float a = bc2[0];
        #pragma unroll
        for (int i = 0; i < 32; i++) a += sz[i] * Wc2[i];
        out[0] = 1.0f / (1.0f + expf(-a));
    }
}

extern "C" void kernel_launch(void* const* d_in, const int* in_sizes, int n_in,
                              void* d_out, int out_size, void* d_ws, size_t ws_size,
                              hipStream_t stream) {
    const float* x   = (const float*)d_in[0];
    const int*   ei  = (const int*)d_in[1];
    const int*   src = ei;
    const int*   dst = ei + E_EDGES;
    const float* W1l = (const float*)d_in[2];
    const float* W1r = (const float*)d_in[3];
    const float* b1  = (const float*)d_in[4];
    const float* W2l = (const float*)d_in[5];
    const float* W2r = (const float*)d_in[6];
    const float* b2  = (const float*)d_in[7];
    const float* Wa  = (const float*)d_in[8];
    const float* ba  = (const float*)d_in[9];
    const float* ctx = (const float*)d_in[10];
    const float* Wc1 = (const float*)d_in[11];
    const float* bc1 = (const float*)d_in[12];
    const float* Wc2 = (const float*)d_in[13];
    const float* bc2 = (const float*)d_in[14];

    char* p = (char*)d_ws;
    int* cnt    = (int*)p;                 p += (size_t)N_NODES * 4;
    int* rowptr = (int*)p;                 p += (size_t)N_NODES * 4;
    int* rowcur = (int*)p;                 p += (size_t)N_NODES * 4;
    int* bsum   = (int*)p;                 p += 128 * 4;
    int* bscan  = (int*)p;                 p += 128 * 4;
    int* ssrc   = (int*)p;                 p += (size_t)E_EDGES * 4;
    uint32* xb  = (uint32*)p;              p += (size_t)N_NODES * 32 * 4;
    uint32* xq  = (uint32*)p;              p += (size_t)N_NODES * 16 * 4;
    uint32* vq  = (uint32*)p;              p += (size_t)N_NODES * 16 * 4;
    float* r2f  = (float*)p;               p += (size_t)N_NODES * 64 * 4;
    ushort* wt1g = (ushort*)p;             p += 128 * 128 * 2;
    ushort* wt2g = (ushort*)p;             p += 128 * 128 * 2;
    float* pooledP = (float*)p;            p += NPART * 64 * 4;
    float* Zpart   = (float*)p;            p += NPART * 4;

    hipMemsetAsync(cnt, 0, (size_t)N_NODES * 4, stream);
    hipMemsetAsync(pooledP, 0, (NPART * 64 + NPART) * 4, stream);

    k_xcast<<<(N_NODES * 16 + 255) / 256, 256, 0, stream>>>(x, xb, xq);
    k_prep<<<2, 256, 0, stream>>>(W1l, W1r, W2l, W2r, wt1g, wt2g);
    k_hist<<<(E_EDGES + 255) / 256, 256, 0, stream>>>(dst, cnt);
    k_scan1<<<NB_SCAN, 256, 0, stream>>>(cnt, bsum);
    k_scan2<<<1, 128, 0, stream>>>(bsum, bscan);
    k_scan3<<<NB_SCAN, 256, 0, stream>>>(cnt, bscan, rowptr, rowcur);
    k_scatter<<<1024, 256, 0, stream>>>(src, dst, rowcur, ssrc);

    k_layer1<<<(N_NODES + 31) / 32, 256, 0, stream>>>(xq, xb, ssrc, rowptr, cnt,
                                                      wt1g, wt2g, b1, b2, vq, r2f);
    k_gather2f<<<(N_NODES + 31) / 32, 256, 0, stream>>>(x, vq, ssrc, rowptr, cnt, r2f,
                                                        Wa, ba, ctx, pooledP, Zpart);
    k_final<<<1, 64, 0, stream>>>(pooledP, Zpart, Wc1, bc1, Wc2, bc2, (float*)d_out);
}